// Round 1
// baseline (497.518 us; speedup 1.0000x reference)
//
#include <hip/hip_runtime.h>
#include <cmath>
#include <cstdint>

typedef __bf16 bf16;
typedef bf16 bf16x4 __attribute__((ext_vector_type(4)));
typedef bf16 bf16x8 __attribute__((ext_vector_type(8)));
typedef float f32x4 __attribute__((ext_vector_type(4)));
typedef unsigned int u32;
typedef u32 u32x4 __attribute__((ext_vector_type(4)));

#define EPS 1e-5f

__device__ __forceinline__ float clipf(float v) {
    return fminf(fmaxf(v, -10000.0f), 10000.0f);
}
__device__ __forceinline__ float fin0(float v) { return isfinite(v) ? v : 0.0f; }

__device__ __forceinline__ void async_copy16(void* lds, const void* g) {
    __builtin_amdgcn_global_load_lds((__attribute__((address_space(1))) void*)(void*)g,
                                     (__attribute__((address_space(3))) void*)lds,
                                     16, 0, 0);
}

// ---------------- convert fp32 -> bf16 with zero padding ----------------
// grid: (outRows, outCols/256). out[r][c] = (r<inRows && c<inCols) ? in : 0
__global__ __launch_bounds__(256) void convert_pad(const float* __restrict__ in,
                                                   bf16* __restrict__ out,
                                                   int inRows, int inCols, int outCols) {
    int r = blockIdx.x;
    int c = blockIdx.y * 256 + threadIdx.x;
    float v = (r < inRows && c < inCols) ? in[(size_t)r * inCols + c] : 0.0f;
    out[(size_t)r * outCols + c] = (bf16)v;
}

// ---------------- block reduction helper (256 threads) ----------------
__device__ __forceinline__ float blockReduceSum(float v, float* sbuf) {
    #pragma unroll
    for (int off = 32; off >= 1; off >>= 1) v += __shfl_xor(v, off, 64);
    int w = threadIdx.x >> 6;
    __syncthreads();
    if ((threadIdx.x & 63) == 0) sbuf[w] = v;
    __syncthreads();
    return sbuf[0] + sbuf[1] + sbuf[2] + sbuf[3];
}

// ---------------- rmsnorm over D=1024, fp32 in -> bf16 out ----------------
__global__ __launch_bounds__(256) void rmsnorm_in(const float* __restrict__ x,
                                                  const float* __restrict__ w,
                                                  bf16* __restrict__ out) {
    __shared__ float sred[4];
    int row = blockIdx.x, t = threadIdx.x;
    f32x4 xv = ((const f32x4*)(x + (size_t)row * 1024))[t];
    f32x4 cv;
    cv[0] = clipf(xv[0]); cv[1] = clipf(xv[1]); cv[2] = clipf(xv[2]); cv[3] = clipf(xv[3]);
    float ss = cv[0]*cv[0] + cv[1]*cv[1] + cv[2]*cv[2] + cv[3]*cv[3];
    float tot = blockReduceSum(ss, sred);
    float rms = sqrtf(fmaxf(tot * (1.0f / 1024.0f), EPS) + EPS);
    f32x4 wv = ((const f32x4*)w)[t];
    bf16x4 o;
    o[0] = (bf16)fin0(cv[0] / rms * wv[0]);
    o[1] = (bf16)fin0(cv[1] / rms * wv[1]);
    o[2] = (bf16)fin0(cv[2] / rms * wv[2]);
    o[3] = (bf16)fin0(cv[3] / rms * wv[3]);
    *(bf16x4*)(out + (size_t)row * 1024 + t * 4) = o;
}

// ---------------- h = x + rmsnorm(a, w_post); optionally hn = rmsnorm(h, w_next) ----------------
template <bool EMIT>
__global__ __launch_bounds__(256) void resid_norm(const float* __restrict__ xres,
                                                  const bf16* __restrict__ a,
                                                  const float* __restrict__ wpost,
                                                  const float* __restrict__ wnext,
                                                  float* __restrict__ hout,
                                                  bf16* __restrict__ hnout) {
    __shared__ float sred[4];
    int row = blockIdx.x, t = threadIdx.x;
    bf16x4 av = *(const bf16x4*)(a + (size_t)row * 1024 + t * 4);
    f32x4 af;
    af[0] = clipf((float)av[0]); af[1] = clipf((float)av[1]);
    af[2] = clipf((float)av[2]); af[3] = clipf((float)av[3]);
    float ss = af[0]*af[0] + af[1]*af[1] + af[2]*af[2] + af[3]*af[3];
    float tot = blockReduceSum(ss, sred);
    float rms1 = sqrtf(fmaxf(tot * (1.0f / 1024.0f), EPS) + EPS);
    f32x4 xv = ((const f32x4*)(xres + (size_t)row * 1024))[t];
    f32x4 wp = ((const f32x4*)wpost)[t];
    f32x4 hv;
    hv[0] = xv[0] + fin0(af[0] / rms1 * wp[0]);
    hv[1] = xv[1] + fin0(af[1] / rms1 * wp[1]);
    hv[2] = xv[2] + fin0(af[2] / rms1 * wp[2]);
    hv[3] = xv[3] + fin0(af[3] / rms1 * wp[3]);
    ((f32x4*)(hout + (size_t)row * 1024))[t] = hv;
    if (EMIT) {
        f32x4 cv;
        cv[0] = clipf(hv[0]); cv[1] = clipf(hv[1]); cv[2] = clipf(hv[2]); cv[3] = clipf(hv[3]);
        float ss2 = cv[0]*cv[0] + cv[1]*cv[1] + cv[2]*cv[2] + cv[3]*cv[3];
        float tot2 = blockReduceSum(ss2, sred);
        float rms2 = sqrtf(fmaxf(tot2 * (1.0f / 1024.0f), EPS) + EPS);
        f32x4 wn = ((const f32x4*)wnext)[t];
        bf16x4 o;
        o[0] = (bf16)fin0(cv[0] / rms2 * wn[0]);
        o[1] = (bf16)fin0(cv[1] / rms2 * wn[1]);
        o[2] = (bf16)fin0(cv[2] / rms2 * wn[2]);
        o[3] = (bf16)fin0(cv[3] / rms2 * wn[3]);
        *(bf16x4*)(hnout + (size_t)row * 1024 + t * 4) = o;
    }
}

// ---------------- per-head rmsnorm (rows of 64), in-place bf16 ----------------
// grid: (nrows/4, 2)  y: 0 -> q buffer, 1 -> k buffer
__global__ __launch_bounds__(256) void head_norm(bf16* __restrict__ q, bf16* __restrict__ k,
                                                 const float* __restrict__ qw,
                                                 const float* __restrict__ kw) {
    bf16* buf = blockIdx.y ? k : q;
    const float* w = blockIdx.y ? kw : qw;
    int row = blockIdx.x * 4 + (threadIdx.x >> 6);
    int lane = threadIdx.x & 63;
    size_t idx = (size_t)row * 64 + lane;
    float v = clipf((float)buf[idx]);
    float ss = v * v;
    #pragma unroll
    for (int off = 32; off >= 1; off >>= 1) ss += __shfl_xor(ss, off, 64);
    float rms = sqrtf(fmaxf(ss * (1.0f / 64.0f), EPS) + EPS);
    buf[idx] = (bf16)fin0(v / rms * w[lane]);
}

// ---------------- GEMM: C[M,N] = A[M,K] * B[N,K]^T + bias, all bf16, fp32 acc ----------------
// grid: (M/128, N/128, nz). z selects B/bias/C pointer set.
__global__ __launch_bounds__(256) void gemm_bt(const bf16* __restrict__ A,
                                               const bf16* __restrict__ B0,
                                               const bf16* __restrict__ B1,
                                               const bf16* __restrict__ B2,
                                               const float* __restrict__ g0,
                                               const float* __restrict__ g1,
                                               const float* __restrict__ g2,
                                               bf16* __restrict__ C0,
                                               bf16* __restrict__ C1,
                                               bf16* __restrict__ C2,
                                               int nBias, int N, int K) {
    int z = blockIdx.z;
    const bf16* B = (z == 0) ? B0 : (z == 1) ? B1 : B2;
    const float* bias = (z == 0) ? g0 : (z == 1) ? g1 : g2;
    bf16* C = (z == 0) ? C0 : (z == 1) ? C1 : C2;

    __shared__ __align__(16) bf16 sA[128 * 32];
    __shared__ __align__(16) bf16 sB[128 * 32];
    const int tid = threadIdx.x;
    const int w = tid >> 6, lane = tid & 63;
    const int m0 = blockIdx.x * 128;
    const int n0 = blockIdx.y * 128;
    const int mw = (w >> 1) * 64, nw = (w & 1) * 64;
    const int r16 = lane & 15, quad = lane >> 4;
    const int kreg = quad * 8;

    f32x4 zero = {0.f, 0.f, 0.f, 0.f};
    f32x4 acc[4][4];
    #pragma unroll
    for (int i = 0; i < 4; ++i)
        #pragma unroll
        for (int j = 0; j < 4; ++j) acc[i][j] = zero;

    const int c0 = tid, c1 = tid + 256;
    const int am0 = c0 >> 2, ak0 = (c0 & 3) << 3;
    const int am1 = c1 >> 2, ak1 = (c1 & 3) << 3;
    const int kIters = K >> 5;

    for (int kt = 0; kt < kIters; ++kt) {
        const int kb = kt << 5;
        __syncthreads();
        async_copy16(&sA[c0 * 8], &A[(size_t)(m0 + am0) * K + kb + ak0]);
        async_copy16(&sA[c1 * 8], &A[(size_t)(m0 + am1) * K + kb + ak1]);
        async_copy16(&sB[c0 * 8], &B[(size_t)(n0 + am0) * K + kb + ak0]);
        async_copy16(&sB[c1 * 8], &B[(size_t)(n0 + am1) * K + kb + ak1]);
        __syncthreads();

        bf16x8 af[4], bf_[4];
        #pragma unroll
        for (int i = 0; i < 4; ++i)
            af[i] = *(const bf16x8*)&sA[(mw + i * 16 + r16) * 32 + kreg];
        #pragma unroll
        for (int i = 0; i < 4; ++i)
            bf_[i] = *(const bf16x8*)&sB[(nw + i * 16 + r16) * 32 + kreg];
        #pragma unroll
        for (int mi = 0; mi < 4; ++mi)
            #pragma unroll
            for (int ni = 0; ni < 4; ++ni)
                acc[mi][ni] = __builtin_amdgcn_mfma_f32_16x16x32_bf16(af[mi], bf_[ni], acc[mi][ni], 0, 0, 0);
    }

    #pragma unroll
    for (int mi = 0; mi < 4; ++mi) {
        #pragma unroll
        for (int ni = 0; ni < 4; ++ni) {
            int col = n0 + nw + ni * 16 + r16;
            float bv = (col < nBias) ? bias[col] : 0.0f;
            #pragma unroll
            for (int r = 0; r < 4; ++r) {
                int row = m0 + mw + mi * 16 + quad * 4 + r;
                C[(size_t)row * N + col] = (bf16)(acc[mi][ni][r] + bv);
            }
        }
    }
}

// ---------------- windowed causal flash attention ----------------
// grid: (L/64, H, B), block 256. q/k/v laid out (B, L, H, 64) bf16.
__global__ __launch_bounds__(256) void attn_win(const bf16* __restrict__ q,
                                                const bf16* __restrict__ k,
                                                const bf16* __restrict__ v,
                                                const int* __restrict__ winp,
                                                bf16* __restrict__ o) {
    __shared__ __align__(16) bf16 sQ[64 * 64];
    __shared__ __align__(16) bf16 sK[64 * 64];
    __shared__ __align__(16) bf16 sVt[64 * 72];
    __shared__ __align__(16) bf16 sP[64 * 64];
    const int tid = threadIdx.x, w = tid >> 6, lane = tid & 63;
    const int qt = blockIdx.x, h = blockIdx.y, b = blockIdx.z;
    const int q0 = qt * 64;
    const int win = *winp;
    const float scale = 0.125f;  // 64^-0.5
    const int r16 = lane & 15, quad = lane >> 4;

    for (int c = tid; c < 512; c += 256) {
        int qr = c >> 3, col = (c & 7) * 8;
        *(u32x4*)&sQ[qr * 64 + col] =
            *(const u32x4*)&q[(((size_t)b * 1024 + q0 + qr) * 16 + h) * 64 + col];
    }
    __syncthreads();
    bf16x8 aq0 = *(const bf16x8*)&sQ[(w * 16 + r16) * 64 + quad * 8];
    bf16x8 aq1 = *(const bf16x8*)&sQ[(w * 16 + r16) * 64 + 32 + quad * 8];

    float M[4], Lr[4];
    f32x4 zero = {0.f, 0.f, 0.f, 0.f};
    f32x4 accO[4];
    #pragma unroll
    for (int r = 0; r < 4; ++r) { M[r] = -INFINITY; Lr[r] = 0.0f; }
    #pragma unroll
    for (int nf = 0; nf < 4; ++nf) accO[nf] = zero;

    int lo = q0 - (win - 1); if (lo < 0) lo = 0;
    const int kt0 = lo >> 6;

    for (int kt = kt0; kt <= qt; ++kt) {
        __syncthreads();
        for (int c = tid; c < 512; c += 256) {
            int kr = c >> 3, col = (c & 7) * 8;
            *(u32x4*)&sK[kr * 64 + col] =
                *(const u32x4*)&k[(((size_t)b * 1024 + kt * 64 + kr) * 16 + h) * 64 + col];
        }
        for (int e = tid; e < 4096; e += 256) {
            int key = e >> 6, hd = e & 63;
            sVt[hd * 72 + key] = v[(((size_t)b * 1024 + kt * 64 + key) * 16 + h) * 64 + hd];
        }
        __syncthreads();

        f32x4 sf[4];
        #pragma unroll
        for (int nf = 0; nf < 4; ++nf) {
            bf16x8 bk0 = *(const bf16x8*)&sK[(nf * 16 + r16) * 64 + quad * 8];
            bf16x8 bk1 = *(const bf16x8*)&sK[(nf * 16 + r16) * 64 + 32 + quad * 8];
            f32x4 accS = zero;
            accS = __builtin_amdgcn_mfma_f32_16x16x32_bf16(aq0, bk0, accS, 0, 0, 0);
            accS = __builtin_amdgcn_mfma_f32_16x16x32_bf16(aq1, bk1, accS, 0, 0, 0);
            sf[nf] = accS;
        }

        #pragma unroll
        for (int r = 0; r < 4; ++r) {
            int i = q0 + w * 16 + quad * 4 + r;
            float p[4];
            float rowmax = -INFINITY;
            #pragma unroll
            for (int nf = 0; nf < 4; ++nf) {
                int j = kt * 64 + nf * 16 + r16;
                bool ok = (j <= i) && (i - j < win);
                float sv = ok ? sf[nf][r] * scale : -INFINITY;
                p[nf] = sv;
                rowmax = fmaxf(rowmax, sv);
            }
            #pragma unroll
            for (int off = 1; off < 16; off <<= 1)
                rowmax = fmaxf(rowmax, __shfl_xor(rowmax, off, 64));
            float mnew = fmaxf(M[r], rowmax);
            float alpha = (mnew == M[r]) ? 1.0f : __expf(M[r] - mnew);
            float rs = 0.0f;
            #pragma unroll
            for (int nf = 0; nf < 4; ++nf) {
                float pv = (p[nf] == -INFINITY) ? 0.0f : __expf(p[nf] - mnew);
                rs += pv;
                sP[(w * 16 + quad * 4 + r) * 64 + nf * 16 + r16] = (bf16)pv;
            }
            #pragma unroll
            for (int off = 1; off < 16; off <<= 1) rs += __shfl_xor(rs, off, 64);
            Lr[r] = Lr[r] * alpha + rs;
            M[r] = mnew;
            #pragma unroll
            for (int nf = 0; nf < 4; ++nf) accO[nf][r] = accO[nf][r] * alpha;
        }
        __syncthreads();

        bf16x8 ap0 = *(const bf16x8*)&sP[(w * 16 + r16) * 64 + quad * 8];
        bf16x8 ap1 = *(const bf16x8*)&sP[(w * 16 + r16) * 64 + 32 + quad * 8];
        #pragma unroll
        for (int nf = 0; nf < 4; ++nf) {
            bf16x8 bv0 = *(const bf16x8*)&sVt[(nf * 16 + r16) * 72 + quad * 8];
            bf16x8 bv1 = *(const bf16x8*)&sVt[(nf * 16 + r16) * 72 + 32 + quad * 8];
            accO[nf] = __builtin_amdgcn_mfma_f32_16x16x32_bf16(ap0, bv0, accO[nf], 0, 0, 0);
            accO[nf] = __builtin_amdgcn_mfma_f32_16x16x32_bf16(ap1, bv1, accO[nf], 0, 0, 0);
        }
    }

    #pragma unroll
    for (int r = 0; r < 4; ++r) {
        float inv = (Lr[r] > 0.0f) ? 1.0f / Lr[r] : 0.0f;
        int row = q0 + w * 16 + quad * 4 + r;
        #pragma unroll
        for (int nf = 0; nf < 4; ++nf) {
            float ov = fin0(accO[nf][r] * inv);
            o[(((size_t)b * 1024 + row) * 16 + h) * 64 + nf * 16 + r16] = (bf16)ov;
        }
    }
}

// ---------------- g = silu(z1) * z3 ----------------
__global__ __launch_bounds__(256) void silu_mul(const bf16* __restrict__ z1,
                                                const bf16* __restrict__ z3,
                                                bf16* __restrict__ g) {
    size_t i = ((size_t)blockIdx.x * 256 + threadIdx.x) * 8;
    bf16x8 a = *(const bf16x8*)(z1 + i);
    bf16x8 b = *(const bf16x8*)(z3 + i);
    bf16x8 o;
    #pragma unroll
    for (int j = 0; j < 8; ++j) {
        float x = (float)a[j];
        float s = x / (1.0f + __expf(-x));
        o[j] = (bf16)(s * (float)b[j]);
    }
    *(bf16x8*)(g + i) = o;
}

extern "C" void kernel_launch(void* const* d_in, const int* in_sizes, int n_in,
                              void* d_out, int out_size, void* d_ws, size_t ws_size,
                              hipStream_t stream) {
    const float* x       = (const float*)d_in[0];
    const float* wq_w    = (const float*)d_in[1];
    const float* wq_b    = (const float*)d_in[2];
    const float* wk_w    = (const float*)d_in[3];
    const float* wk_b    = (const float*)d_in[4];
    const float* wv_w    = (const float*)d_in[5];
    const float* wv_b    = (const float*)d_in[6];
    const float* wo_w    = (const float*)d_in[7];
    const float* wo_b    = (const float*)d_in[8];
    const float* q_norm_w= (const float*)d_in[9];
    const float* k_norm_w= (const float*)d_in[10];
    const float* seq_norm_w      = (const float*)d_in[11];
    const float* seq_post_norm_w = (const float*)d_in[12];
    const float* ffn_norm_w      = (const float*)d_in[13];
    const float* ffn_post_norm_w = (const float*)d_in[14];
    const float* w1_w    = (const float*)d_in[15];
    const float* w1_b    = (const float*)d_in[16];
    const float* w2_w    = (const float*)d_in[17];
    const float* w2_b    = (const float*)d_in[18];
    const float* w3_w    = (const float*)d_in[19];
    const float* w3_b    = (const float*)d_in[20];
    const int*   winp    = (const int*)d_in[21];
    float* out = (float*)d_out;

    const size_t SZ_W   = 2097152;    // 1024*1024*2
    const size_t SZ_WP  = 6815744;    // 3328*1024*2
    const size_t SZ_ACT = 8388608;    // 4096*1024*2
    const size_t SZ_H   = 16777216;   // 4096*1024*4
    const size_t SZ_Z   = 27262976;   // 4096*3328*2

    char* p = (char*)d_ws;
    bf16* Wq  = (bf16*)p; p += SZ_W;
    bf16* Wk  = (bf16*)p; p += SZ_W;
    bf16* Wv  = (bf16*)p; p += SZ_W;
    bf16* Wo  = (bf16*)p; p += SZ_W;
    bf16* W1p = (bf16*)p; p += SZ_WP;
    bf16* W3p = (bf16*)p; p += SZ_WP;
    bf16* W2p = (bf16*)p; p += SZ_WP;
    float* h  = (float*)p; p += SZ_H;
    bf16* hn  = (bf16*)p; p += SZ_ACT;
    bf16* fb  = (bf16*)p; p += SZ_ACT;
    char* regionA = p;  // aliased region: attention-phase buffers, then FFN z1/z3/g
    bf16* xn    = (bf16*)(regionA);
    bf16* qb    = (bf16*)(regionA + 1 * SZ_ACT);
    bf16* kb    = (bf16*)(regionA + 2 * SZ_ACT);
    bf16* vb    = (bf16*)(regionA + 3 * SZ_ACT);
    bf16* attnb = (bf16*)(regionA + 4 * SZ_ACT);
    bf16* ab    = (bf16*)(regionA + 5 * SZ_ACT);
    bf16* z1 = (bf16*)(regionA);
    bf16* z3 = (bf16*)(regionA + SZ_Z);
    bf16* g  = (bf16*)(regionA + 2 * SZ_Z);

    dim3 blk(256);

    // weight conversion (padded for FFN dims: 3280 -> 3328)
    convert_pad<<<dim3(1024, 4, 1), blk, 0, stream>>>(wq_w, Wq, 1024, 1024, 1024);
    convert_pad<<<dim3(1024, 4, 1), blk, 0, stream>>>(wk_w, Wk, 1024, 1024, 1024);
    convert_pad<<<dim3(1024, 4, 1), blk, 0, stream>>>(wv_w, Wv, 1024, 1024, 1024);
    convert_pad<<<dim3(1024, 4, 1), blk, 0, stream>>>(wo_w, Wo, 1024, 1024, 1024);
    convert_pad<<<dim3(3328, 4, 1), blk, 0, stream>>>(w1_w, W1p, 3280, 1024, 1024);
    convert_pad<<<dim3(3328, 4, 1), blk, 0, stream>>>(w3_w, W3p, 3280, 1024, 1024);
    convert_pad<<<dim3(1024, 13, 1), blk, 0, stream>>>(w2_w, W2p, 1024, 3280, 3328);

    // xn = rmsnorm(x, seq_norm_w)
    rmsnorm_in<<<4096, blk, 0, stream>>>(x, seq_norm_w, xn);

    // q/k/v projections (fused via grid.z)
    gemm_bt<<<dim3(32, 8, 3), blk, 0, stream>>>(xn, Wq, Wk, Wv, wq_b, wk_b, wv_b,
                                                qb, kb, vb, 1024, 1024, 1024);
    // per-head q/k rmsnorm, in place
    head_norm<<<dim3(16384, 2, 1), blk, 0, stream>>>(qb, kb, q_norm_w, k_norm_w);

    // windowed causal attention
    attn_win<<<dim3(16, 16, 4), blk, 0, stream>>>(qb, kb, vb, winp, attnb);

    // output projection
    gemm_bt<<<dim3(32, 8, 1), blk, 0, stream>>>(attnb, Wo, Wo, Wo, wo_b, wo_b, wo_b,
                                                ab, ab, ab, 1024, 1024, 1024);

    // h = x + rmsnorm(a, seq_post_norm_w); hn = rmsnorm(h, ffn_norm_w)
    resid_norm<true><<<4096, blk, 0, stream>>>(x, ab, seq_post_norm_w, ffn_norm_w, h, hn);

    // z1 = hn @ w1^T + b1 ; z3 = hn @ w3^T + b3 (fused via grid.z), N padded to 3328
    gemm_bt<<<dim3(32, 26, 2), blk, 0, stream>>>(hn, W1p, W3p, W3p, w1_b, w3_b, w3_b,
                                                 z1, z3, z3, 3280, 3328, 1024);
    // g = silu(z1) * z3
    silu_mul<<<6656, blk, 0, stream>>>(z1, z3, g);

    // f = g @ w2^T + b2 (K padded to 3328; padded cols of g are exactly zero)
    gemm_bt<<<dim3(32, 8, 1), blk, 0, stream>>>(g, W2p, W2p, W2p, w2_b, w2_b, w2_b,
                                                fb, fb, fb, 1024, 1024, 3328);

    // out = h + rmsnorm(f, ffn_post_norm_w)
    resid_norm<false><<<4096, blk, 0, stream>>>(h, fb, ffn_post_norm_w, nullptr, out, nullptr);
}

// Round 2
// 469.647 us; speedup vs baseline: 1.0593x; 1.0593x over previous
//
#include <hip/hip_runtime.h>
#include <cmath>
#include <cstdint>

typedef __bf16 bf16;
typedef bf16 bf16x4 __attribute__((ext_vector_type(4)));
typedef bf16 bf16x8 __attribute__((ext_vector_type(8)));
typedef float f32x4 __attribute__((ext_vector_type(4)));
typedef unsigned int u32;
typedef u32 u32x4 __attribute__((ext_vector_type(4)));

#define EPS 1e-5f

__device__ __forceinline__ float clipf(float v) {
    return fminf(fmaxf(v, -10000.0f), 10000.0f);
}
__device__ __forceinline__ float fin0(float v) { return isfinite(v) ? v : 0.0f; }

__device__ __forceinline__ void async_copy16(void* lds, const void* g) {
    __builtin_amdgcn_global_load_lds((__attribute__((address_space(1))) void*)(void*)g,
                                     (__attribute__((address_space(3))) void*)lds,
                                     16, 0, 0);
}

// ---------------- weight converts (fp32 -> bf16, optional zero pad) ----------------
// 4 square weights, grid (1024, 4, 4)
__global__ __launch_bounds__(256) void convert4(const float* __restrict__ i0, const float* __restrict__ i1,
                                                const float* __restrict__ i2, const float* __restrict__ i3,
                                                bf16* __restrict__ o0, bf16* __restrict__ o1,
                                                bf16* __restrict__ o2, bf16* __restrict__ o3) {
    int z = blockIdx.z;
    const float* in = (z == 0) ? i0 : (z == 1) ? i1 : (z == 2) ? i2 : i3;
    bf16* out = (z == 0) ? o0 : (z == 1) ? o1 : (z == 2) ? o2 : o3;
    int r = blockIdx.x;
    int c = blockIdx.y * 256 + threadIdx.x;
    out[(size_t)r * 1024 + c] = (bf16)in[(size_t)r * 1024 + c];
}

// w1/w3: rows 3280 -> 3328 (pad rows), cols 1024. grid (3328, 4, 2)
__global__ __launch_bounds__(256) void convert_w13(const float* __restrict__ i0, const float* __restrict__ i1,
                                                   bf16* __restrict__ o0, bf16* __restrict__ o1) {
    const float* in = blockIdx.z ? i1 : i0;
    bf16* out = blockIdx.z ? o1 : o0;
    int r = blockIdx.x;
    int c = blockIdx.y * 256 + threadIdx.x;
    float v = (r < 3280) ? in[(size_t)r * 1024 + c] : 0.0f;
    out[(size_t)r * 1024 + c] = (bf16)v;
}

// w2: 1024 x 3280 -> 1024 x 3328 (pad cols). grid (1024, 13)
__global__ __launch_bounds__(256) void convert_w2(const float* __restrict__ in, bf16* __restrict__ out) {
    int r = blockIdx.x;
    int c = blockIdx.y * 256 + threadIdx.x;
    float v = (c < 3280) ? in[(size_t)r * 3280 + c] : 0.0f;
    out[(size_t)r * 3328 + c] = (bf16)v;
}

// ---------------- block reduction helper (256 threads) ----------------
__device__ __forceinline__ float blockReduceSum(float v, float* sbuf) {
    #pragma unroll
    for (int off = 32; off >= 1; off >>= 1) v += __shfl_xor(v, off, 64);
    int w = threadIdx.x >> 6;
    __syncthreads();
    if ((threadIdx.x & 63) == 0) sbuf[w] = v;
    __syncthreads();
    return sbuf[0] + sbuf[1] + sbuf[2] + sbuf[3];
}

// ---------------- rmsnorm over D=1024, fp32 in -> bf16 out ----------------
__global__ __launch_bounds__(256) void rmsnorm_in(const float* __restrict__ x,
                                                  const float* __restrict__ w,
                                                  bf16* __restrict__ out) {
    __shared__ float sred[4];
    int row = blockIdx.x, t = threadIdx.x;
    f32x4 xv = ((const f32x4*)(x + (size_t)row * 1024))[t];
    f32x4 cv;
    cv[0] = clipf(xv[0]); cv[1] = clipf(xv[1]); cv[2] = clipf(xv[2]); cv[3] = clipf(xv[3]);
    float ss = cv[0]*cv[0] + cv[1]*cv[1] + cv[2]*cv[2] + cv[3]*cv[3];
    float tot = blockReduceSum(ss, sred);
    float rms = sqrtf(fmaxf(tot * (1.0f / 1024.0f), EPS) + EPS);
    f32x4 wv = ((const f32x4*)w)[t];
    bf16x4 o;
    o[0] = (bf16)fin0(cv[0] / rms * wv[0]);
    o[1] = (bf16)fin0(cv[1] / rms * wv[1]);
    o[2] = (bf16)fin0(cv[2] / rms * wv[2]);
    o[3] = (bf16)fin0(cv[3] / rms * wv[3]);
    *(bf16x4*)(out + (size_t)row * 1024 + t * 4) = o;
}

// ---------------- resid+norm: a = p0+p1+bias; h = x + rmsnorm(a, wpost); opt hn = rmsnorm(h, wnext) ----------------
template <bool EMIT>
__global__ __launch_bounds__(256) void resid_norm(const float* __restrict__ xres,
                                                  const float* __restrict__ p0,
                                                  const float* __restrict__ p1,
                                                  const float* __restrict__ bias,
                                                  const float* __restrict__ wpost,
                                                  const float* __restrict__ wnext,
                                                  float* __restrict__ hout,
                                                  bf16* __restrict__ hnout) {
    __shared__ float sred[4];
    int row = blockIdx.x, t = threadIdx.x;
    f32x4 a0 = ((const f32x4*)(p0 + (size_t)row * 1024))[t];
    f32x4 a1 = ((const f32x4*)(p1 + (size_t)row * 1024))[t];
    f32x4 bv = ((const f32x4*)bias)[t];
    f32x4 af;
    af[0] = clipf(a0[0] + a1[0] + bv[0]);
    af[1] = clipf(a0[1] + a1[1] + bv[1]);
    af[2] = clipf(a0[2] + a1[2] + bv[2]);
    af[3] = clipf(a0[3] + a1[3] + bv[3]);
    float ss = af[0]*af[0] + af[1]*af[1] + af[2]*af[2] + af[3]*af[3];
    float tot = blockReduceSum(ss, sred);
    float rms1 = sqrtf(fmaxf(tot * (1.0f / 1024.0f), EPS) + EPS);
    f32x4 xv = ((const f32x4*)(xres + (size_t)row * 1024))[t];
    f32x4 wp = ((const f32x4*)wpost)[t];
    f32x4 hv;
    hv[0] = xv[0] + fin0(af[0] / rms1 * wp[0]);
    hv[1] = xv[1] + fin0(af[1] / rms1 * wp[1]);
    hv[2] = xv[2] + fin0(af[2] / rms1 * wp[2]);
    hv[3] = xv[3] + fin0(af[3] / rms1 * wp[3]);
    ((f32x4*)(hout + (size_t)row * 1024))[t] = hv;
    if (EMIT) {
        f32x4 cv;
        cv[0] = clipf(hv[0]); cv[1] = clipf(hv[1]); cv[2] = clipf(hv[2]); cv[3] = clipf(hv[3]);
        float ss2 = cv[0]*cv[0] + cv[1]*cv[1] + cv[2]*cv[2] + cv[3]*cv[3];
        float tot2 = blockReduceSum(ss2, sred);
        float rms2 = sqrtf(fmaxf(tot2 * (1.0f / 1024.0f), EPS) + EPS);
        f32x4 wn = ((const f32x4*)wnext)[t];
        bf16x4 o;
        o[0] = (bf16)fin0(cv[0] / rms2 * wn[0]);
        o[1] = (bf16)fin0(cv[1] / rms2 * wn[1]);
        o[2] = (bf16)fin0(cv[2] / rms2 * wn[2]);
        o[3] = (bf16)fin0(cv[3] / rms2 * wn[3]);
        *(bf16x4*)(hnout + (size_t)row * 1024 + t * 4) = o;
    }
}

// ---------------- QKV GEMM with fused per-head rmsnorm (q,k) ----------------
// C[M,1024] = A[M,1024] @ B[1024,1024]^T + bias; z in {q,k,v}. grid (M/128, 8, 3)
__global__ __launch_bounds__(256) void gemm_qkv(const bf16* __restrict__ A,
                                                const bf16* __restrict__ B0,
                                                const bf16* __restrict__ B1,
                                                const bf16* __restrict__ B2,
                                                const float* __restrict__ g0,
                                                const float* __restrict__ g1,
                                                const float* __restrict__ g2,
                                                const float* __restrict__ qnw,
                                                const float* __restrict__ knw,
                                                bf16* __restrict__ C0,
                                                bf16* __restrict__ C1,
                                                bf16* __restrict__ C2) {
    const int z = blockIdx.z;
    const bf16* B = (z == 0) ? B0 : (z == 1) ? B1 : B2;
    const float* bias = (z == 0) ? g0 : (z == 1) ? g1 : g2;
    bf16* C = (z == 0) ? C0 : (z == 1) ? C1 : C2;
    const float* hw = (z == 0) ? qnw : knw;

    __shared__ __align__(16) bf16 sA[128 * 32];
    __shared__ __align__(16) bf16 sB[128 * 32];
    const int tid = threadIdx.x;
    const int w = tid >> 6, lane = tid & 63;
    const int m0 = blockIdx.x * 128;
    const int n0 = blockIdx.y * 128;
    const int mwo = (w >> 1) * 64, nwo = (w & 1) * 64;
    const int r16 = lane & 15, quad = lane >> 4;
    const int kreg = quad * 8;
    const int K = 1024, N = 1024;

    f32x4 zero = {0.f, 0.f, 0.f, 0.f};
    f32x4 acc[4][4];
    #pragma unroll
    for (int i = 0; i < 4; ++i)
        #pragma unroll
        for (int j = 0; j < 4; ++j) acc[i][j] = zero;

    const int c0 = tid, c1 = tid + 256;
    const int am0 = c0 >> 2, ak0 = (c0 & 3) << 3;
    const int am1 = c1 >> 2, ak1 = (c1 & 3) << 3;

    for (int kt = 0; kt < 32; ++kt) {
        const int kb = kt << 5;
        __syncthreads();
        async_copy16(&sA[c0 * 8], &A[(size_t)(m0 + am0) * K + kb + ak0]);
        async_copy16(&sA[c1 * 8], &A[(size_t)(m0 + am1) * K + kb + ak1]);
        async_copy16(&sB[c0 * 8], &B[(size_t)(n0 + am0) * K + kb + ak0]);
        async_copy16(&sB[c1 * 8], &B[(size_t)(n0 + am1) * K + kb + ak1]);
        __syncthreads();

        bf16x8 af[4], bfr[4];
        #pragma unroll
        for (int i = 0; i < 4; ++i)
            af[i] = *(const bf16x8*)&sA[(mwo + i * 16 + r16) * 32 + kreg];
        #pragma unroll
        for (int i = 0; i < 4; ++i)
            bfr[i] = *(const bf16x8*)&sB[(nwo + i * 16 + r16) * 32 + kreg];
        #pragma unroll
        for (int mi = 0; mi < 4; ++mi)
            #pragma unroll
            for (int ni = 0; ni < 4; ++ni)
                acc[mi][ni] = __builtin_amdgcn_mfma_f32_16x16x32_bf16(af[mi], bfr[ni], acc[mi][ni], 0, 0, 0);
    }

    float bv[4], nwv[4];
    #pragma unroll
    for (int ni = 0; ni < 4; ++ni) {
        int col = n0 + nwo + ni * 16 + r16;
        bv[ni] = bias[col];
        nwv[ni] = (z < 2) ? hw[ni * 16 + r16] : 0.0f;  // col % 64 == ni*16 + r16
    }

    if (z < 2) {
        // fused per-head rmsnorm: each wave tile spans exactly one 64-wide head
        #pragma unroll
        for (int mi = 0; mi < 4; ++mi) {
            #pragma unroll
            for (int r = 0; r < 4; ++r) {
                float v[4], ss = 0.0f;
                #pragma unroll
                for (int ni = 0; ni < 4; ++ni) {
                    v[ni] = clipf(acc[mi][ni][r] + bv[ni]);
                    ss += v[ni] * v[ni];
                }
                ss += __shfl_xor(ss, 1, 64);
                ss += __shfl_xor(ss, 2, 64);
                ss += __shfl_xor(ss, 4, 64);
                ss += __shfl_xor(ss, 8, 64);
                float rms = sqrtf(fmaxf(ss * (1.0f / 64.0f), EPS) + EPS);
                int row = m0 + mwo + mi * 16 + quad * 4 + r;
                #pragma unroll
                for (int ni = 0; ni < 4; ++ni) {
                    int col = n0 + nwo + ni * 16 + r16;
                    C[(size_t)row * N + col] = (bf16)fin0(v[ni] / rms * nwv[ni]);
                }
            }
        }
    } else {
        #pragma unroll
        for (int mi = 0; mi < 4; ++mi)
            #pragma unroll
            for (int ni = 0; ni < 4; ++ni) {
                int col = n0 + nwo + ni * 16 + r16;
                #pragma unroll
                for (int r = 0; r < 4; ++r) {
                    int row = m0 + mwo + mi * 16 + quad * 4 + r;
                    C[(size_t)row * N + col] = (bf16)(acc[mi][ni][r] + bv[ni]);
                }
            }
    }
}

// ---------------- fused FFN1: g = silu(A@W1^T + b1) * (A@W3^T + b3) ----------------
// A[M,1024], W1/W3[3328,1024], g[M,3328]. grid (M/128, 26)
__global__ __launch_bounds__(256) void gemm_ffn1(const bf16* __restrict__ A,
                                                 const bf16* __restrict__ B1,
                                                 const bf16* __restrict__ B3,
                                                 const float* __restrict__ b1,
                                                 const float* __restrict__ b3,
                                                 bf16* __restrict__ G) {
    __shared__ __align__(16) bf16 sA[128 * 32];
    __shared__ __align__(16) bf16 sB1[128 * 32];
    __shared__ __align__(16) bf16 sB3[128 * 32];
    const int tid = threadIdx.x;
    const int w = tid >> 6, lane = tid & 63;
    const int m0 = blockIdx.x * 128;
    const int n0 = blockIdx.y * 128;
    const int mwo = (w >> 1) * 64, nwo = (w & 1) * 64;
    const int r16 = lane & 15, quad = lane >> 4;
    const int kreg = quad * 8;
    const int K = 1024, N = 3328;

    f32x4 zero = {0.f, 0.f, 0.f, 0.f};
    f32x4 acc1[4][4], acc3[4][4];
    #pragma unroll
    for (int i = 0; i < 4; ++i)
        #pragma unroll
        for (int j = 0; j < 4; ++j) { acc1[i][j] = zero; acc3[i][j] = zero; }

    const int c0 = tid, c1 = tid + 256;
    const int am0 = c0 >> 2, ak0 = (c0 & 3) << 3;
    const int am1 = c1 >> 2, ak1 = (c1 & 3) << 3;

    for (int kt = 0; kt < 32; ++kt) {
        const int kb = kt << 5;
        __syncthreads();
        async_copy16(&sA[c0 * 8], &A[(size_t)(m0 + am0) * K + kb + ak0]);
        async_copy16(&sA[c1 * 8], &A[(size_t)(m0 + am1) * K + kb + ak1]);
        async_copy16(&sB1[c0 * 8], &B1[(size_t)(n0 + am0) * K + kb + ak0]);
        async_copy16(&sB1[c1 * 8], &B1[(size_t)(n0 + am1) * K + kb + ak1]);
        async_copy16(&sB3[c0 * 8], &B3[(size_t)(n0 + am0) * K + kb + ak0]);
        async_copy16(&sB3[c1 * 8], &B3[(size_t)(n0 + am1) * K + kb + ak1]);
        __syncthreads();

        bf16x8 af[4], bf1[4], bf3[4];
        #pragma unroll
        for (int i = 0; i < 4; ++i) {
            af[i]  = *(const bf16x8*)&sA[(mwo + i * 16 + r16) * 32 + kreg];
            bf1[i] = *(const bf16x8*)&sB1[(nwo + i * 16 + r16) * 32 + kreg];
            bf3[i] = *(const bf16x8*)&sB3[(nwo + i * 16 + r16) * 32 + kreg];
        }
        #pragma unroll
        for (int mi = 0; mi < 4; ++mi)
            #pragma unroll
            for (int ni = 0; ni < 4; ++ni) {
                acc1[mi][ni] = __builtin_amdgcn_mfma_f32_16x16x32_bf16(af[mi], bf1[ni], acc1[mi][ni], 0, 0, 0);
                acc3[mi][ni] = __builtin_amdgcn_mfma_f32_16x16x32_bf16(af[mi], bf3[ni], acc3[mi][ni], 0, 0, 0);
            }
    }

    #pragma unroll
    for (int ni = 0; ni < 4; ++ni) {
        int col = n0 + nwo + ni * 16 + r16;
        float bv1 = (col < 3280) ? b1[col] : 0.0f;
        float bv3 = (col < 3280) ? b3[col] : 0.0f;
        #pragma unroll
        for (int mi = 0; mi < 4; ++mi) {
            #pragma unroll
            for (int r = 0; r < 4; ++r) {
                int row = m0 + mwo + mi * 16 + quad * 4 + r;
                float z1 = acc1[mi][ni][r] + bv1;
                float z3 = acc3[mi][ni][r] + bv3;
                float s = z1 / (1.0f + __expf(-z1));
                G[(size_t)row * N + col] = (bf16)(s * z3);
            }
        }
    }
}

// ---------------- split-K GEMM -> f32 partials (no bias) ----------------
// P[s][M][N] = A[M, s*Kh : (s+1)*Kh] @ B[N, ...]^T. grid (M/128, N/128, 2)
__global__ __launch_bounds__(256) void gemm_splitk(const bf16* __restrict__ A,
                                                   const bf16* __restrict__ B,
                                                   float* __restrict__ P,
                                                   int N, int K, int Kh) {
    const int s = blockIdx.z;
    __shared__ __align__(16) bf16 sA[128 * 32];
    __shared__ __align__(16) bf16 sB[128 * 32];
    const int tid = threadIdx.x;
    const int w = tid >> 6, lane = tid & 63;
    const int m0 = blockIdx.x * 128;
    const int n0 = blockIdx.y * 128;
    const int mwo = (w >> 1) * 64, nwo = (w & 1) * 64;
    const int r16 = lane & 15, quad = lane >> 4;
    const int kreg = quad * 8;
    const int kbase = s * Kh;

    f32x4 zero = {0.f, 0.f, 0.f, 0.f};
    f32x4 acc[4][4];
    #pragma unroll
    for (int i = 0; i < 4; ++i)
        #pragma unroll
        for (int j = 0; j < 4; ++j) acc[i][j] = zero;

    const int c0 = tid, c1 = tid + 256;
    const int am0 = c0 >> 2, ak0 = (c0 & 3) << 3;
    const int am1 = c1 >> 2, ak1 = (c1 & 3) << 3;
    const int kIters = Kh >> 5;

    for (int kt = 0; kt < kIters; ++kt) {
        const int kb = kbase + (kt << 5);
        __syncthreads();
        async_copy16(&sA[c0 * 8], &A[(size_t)(m0 + am0) * K + kb + ak0]);
        async_copy16(&sA[c1 * 8], &A[(size_t)(m0 + am1) * K + kb + ak1]);
        async_copy16(&sB[c0 * 8], &B[(size_t)(n0 + am0) * K + kb + ak0]);
        async_copy16(&sB[c1 * 8], &B[(size_t)(n0 + am1) * K + kb + ak1]);
        __syncthreads();

        bf16x8 af[4], bfr[4];
        #pragma unroll
        for (int i = 0; i < 4; ++i) {
            af[i]  = *(const bf16x8*)&sA[(mwo + i * 16 + r16) * 32 + kreg];
            bfr[i] = *(const bf16x8*)&sB[(nwo + i * 16 + r16) * 32 + kreg];
        }
        #pragma unroll
        for (int mi = 0; mi < 4; ++mi)
            #pragma unroll
            for (int ni = 0; ni < 4; ++ni)
                acc[mi][ni] = __builtin_amdgcn_mfma_f32_16x16x32_bf16(af[mi], bfr[ni], acc[mi][ni], 0, 0, 0);
    }

    float* Pz = P + (size_t)s * 4096 * 1024;
    #pragma unroll
    for (int mi = 0; mi < 4; ++mi)
        #pragma unroll
        for (int ni = 0; ni < 4; ++ni) {
            int col = n0 + nwo + ni * 16 + r16;
            #pragma unroll
            for (int r = 0; r < 4; ++r) {
                int row = m0 + mwo + mi * 16 + quad * 4 + r;
                Pz[(size_t)row * N + col] = acc[mi][ni][r];
            }
        }
}

// ---------------- windowed causal flash attention ----------------
// grid: (L/64, H, B), block 256. q/k/v laid out (B, L, H, 64) bf16.
__global__ __launch_bounds__(256) void attn_win(const bf16* __restrict__ q,
                                                const bf16* __restrict__ k,
                                                const bf16* __restrict__ v,
                                                const int* __restrict__ winp,
                                                bf16* __restrict__ o) {
    __shared__ __align__(16) bf16 sQ[64 * 64];
    __shared__ __align__(16) bf16 sK[64 * 64];
    __shared__ __align__(16) bf16 sVt[64 * 72];
    __shared__ __align__(16) bf16 sP[64 * 64];
    const int tid = threadIdx.x, w = tid >> 6, lane = tid & 63;
    const int qt = blockIdx.x, h = blockIdx.y, b = blockIdx.z;
    const int q0 = qt * 64;
    const int win = *winp;
    const float scale = 0.125f;  // 64^-0.5
    const int r16 = lane & 15, quad = lane >> 4;

    for (int c = tid; c < 512; c += 256) {
        int qr = c >> 3, col = (c & 7) * 8;
        *(u32x4*)&sQ[qr * 64 + col] =
            *(const u32x4*)&q[(((size_t)b * 1024 + q0 + qr) * 16 + h) * 64 + col];
    }
    __syncthreads();
    bf16x8 aq0 = *(const bf16x8*)&sQ[(w * 16 + r16) * 64 + quad * 8];
    bf16x8 aq1 = *(const bf16x8*)&sQ[(w * 16 + r16) * 64 + 32 + quad * 8];

    float M[4], Lr[4];
    f32x4 zero = {0.f, 0.f, 0.f, 0.f};
    f32x4 accO[4];
    #pragma unroll
    for (int r = 0; r < 4; ++r) { M[r] = -INFINITY; Lr[r] = 0.0f; }
    #pragma unroll
    for (int nf = 0; nf < 4; ++nf) accO[nf] = zero;

    int lo = q0 - (win - 1); if (lo < 0) lo = 0;
    const int kt0 = lo >> 6;

    for (int kt = kt0; kt <= qt; ++kt) {
        __syncthreads();
        for (int c = tid; c < 512; c += 256) {
            int kr = c >> 3, col = (c & 7) * 8;
            *(u32x4*)&sK[kr * 64 + col] =
                *(const u32x4*)&k[(((size_t)b * 1024 + kt * 64 + kr) * 16 + h) * 64 + col];
        }
        for (int e = tid; e < 4096; e += 256) {
            int key = e >> 6, hd = e & 63;
            sVt[hd * 72 + key] = v[(((size_t)b * 1024 + kt * 64 + key) * 16 + h) * 64 + hd];
        }
        __syncthreads();

        f32x4 sf[4];
        #pragma unroll
        for (int nf = 0; nf < 4; ++nf) {
            bf16x8 bk0 = *(const bf16x8*)&sK[(nf * 16 + r16) * 64 + quad * 8];
            bf16x8 bk1 = *(const bf16x8*)&sK[(nf * 16 + r16) * 64 + 32 + quad * 8];
            f32x4 accS = zero;
            accS = __builtin_amdgcn_mfma_f32_16x16x32_bf16(aq0, bk0, accS, 0, 0, 0);
            accS = __builtin_amdgcn_mfma_f32_16x16x32_bf16(aq1, bk1, accS, 0, 0, 0);
            sf[nf] = accS;
        }

        #pragma unroll
        for (int r = 0; r < 4; ++r) {
            int i = q0 + w * 16 + quad * 4 + r;
            float p[4];
            float rowmax = -INFINITY;
            #pragma unroll
            for (int nf = 0; nf < 4; ++nf) {
                int j = kt * 64 + nf * 16 + r16;
                bool ok = (j <= i) && (i - j < win);
                float sv = ok ? sf[nf][r] * scale : -INFINITY;
                p[nf] = sv;
                rowmax = fmaxf(rowmax, sv);
            }
            #pragma unroll
            for (int off = 1; off < 16; off <<= 1)
                rowmax = fmaxf(rowmax, __shfl_xor(rowmax, off, 64));
            float mnew = fmaxf(M[r], rowmax);
            float alpha = (mnew == M[r]) ? 1.0f : __expf(M[r] - mnew);
            float rs = 0.0f;
            #pragma unroll
            for (int nf = 0; nf < 4; ++nf) {
                float pv = (p[nf] == -INFINITY) ? 0.0f : __expf(p[nf] - mnew);
                rs += pv;
                sP[(w * 16 + quad * 4 + r) * 64 + nf * 16 + r16] = (bf16)pv;
            }
            #pragma unroll
            for (int off = 1; off < 16; off <<= 1) rs += __shfl_xor(rs, off, 64);
            Lr[r] = Lr[r] * alpha + rs;
            M[r] = mnew;
            #pragma unroll
            for (int nf = 0; nf < 4; ++nf) accO[nf][r] = accO[nf][r] * alpha;
        }
        __syncthreads();

        bf16x8 ap0 = *(const bf16x8*)&sP[(w * 16 + r16) * 64 + quad * 8];
        bf16x8 ap1 = *(const bf16x8*)&sP[(w * 16 + r16) * 64 + 32 + quad * 8];
        #pragma unroll
        for (int nf = 0; nf < 4; ++nf) {
            bf16x8 bv0 = *(const bf16x8*)&sVt[(nf * 16 + r16) * 72 + quad * 8];
            bf16x8 bv1 = *(const bf16x8*)&sVt[(nf * 16 + r16) * 72 + 32 + quad * 8];
            accO[nf] = __builtin_amdgcn_mfma_f32_16x16x32_bf16(ap0, bv0, accO[nf], 0, 0, 0);
            accO[nf] = __builtin_amdgcn_mfma_f32_16x16x32_bf16(ap1, bv1, accO[nf], 0, 0, 0);
        }
    }

    #pragma unroll
    for (int r = 0; r < 4; ++r) {
        float inv = (Lr[r] > 0.0f) ? 1.0f / Lr[r] : 0.0f;
        int row = q0 + w * 16 + quad * 4 + r;
        #pragma unroll
        for (int nf = 0; nf < 4; ++nf) {
            float ov = fin0(accO[nf][r] * inv);
            o[(((size_t)b * 1024 + row) * 16 + h) * 64 + nf * 16 + r16] = (bf16)ov;
        }
    }
}

extern "C" void kernel_launch(void* const* d_in, const int* in_sizes, int n_in,
                              void* d_out, int out_size, void* d_ws, size_t ws_size,
                              hipStream_t stream) {
    const float* x       = (const float*)d_in[0];
    const float* wq_w    = (const float*)d_in[1];
    const float* wq_b    = (const float*)d_in[2];
    const float* wk_w    = (const float*)d_in[3];
    const float* wk_b    = (const float*)d_in[4];
    const float* wv_w    = (const float*)d_in[5];
    const float* wv_b    = (const float*)d_in[6];
    const float* wo_w    = (const float*)d_in[7];
    const float* wo_b    = (const float*)d_in[8];
    const float* q_norm_w= (const float*)d_in[9];
    const float* k_norm_w= (const float*)d_in[10];
    const float* seq_norm_w      = (const float*)d_in[11];
    const float* seq_post_norm_w = (const float*)d_in[12];
    const float* ffn_norm_w      = (const float*)d_in[13];
    const float* ffn_post_norm_w = (const float*)d_in[14];
    const float* w1_w    = (const float*)d_in[15];
    const float* w1_b    = (const float*)d_in[16];
    const float* w2_w    = (const float*)d_in[17];
    const float* w2_b    = (const float*)d_in[18];
    const float* w3_w    = (const float*)d_in[19];
    const float* w3_b    = (const float*)d_in[20];
    const int*   winp    = (const int*)d_in[21];
    float* out = (float*)d_out;

    const size_t SZ_W   = 2097152;    // 1024*1024*2
    const size_t SZ_WP  = 6815744;    // 3328*1024*2
    const size_t SZ_ACT = 8388608;    // 4096*1024*2
    const size_t SZ_H   = 16777216;   // 4096*1024*4
    const size_t SZ_P   = 33554432;   // 2*4096*1024*4

    char* p = (char*)d_ws;
    bf16* Wq  = (bf16*)p; p += SZ_W;
    bf16* Wk  = (bf16*)p; p += SZ_W;
    bf16* Wv  = (bf16*)p; p += SZ_W;
    bf16* Wo  = (bf16*)p; p += SZ_W;
    bf16* W1p = (bf16*)p; p += SZ_WP;
    bf16* W3p = (bf16*)p; p += SZ_WP;
    bf16* W2p = (bf16*)p; p += SZ_WP;
    float* h  = (float*)p; p += SZ_H;
    bf16* hn  = (bf16*)p; p += SZ_ACT;
    float* part = (float*)p; p += SZ_P;   // split-K partials (O-proj, then FFN2)
    char* regionA = p;  // aliased: attn-phase buffers, later g
    bf16* xn    = (bf16*)(regionA);
    bf16* qb    = (bf16*)(regionA + 1 * SZ_ACT);
    bf16* kb    = (bf16*)(regionA + 2 * SZ_ACT);
    bf16* vb    = (bf16*)(regionA + 3 * SZ_ACT);
    bf16* attnb = (bf16*)(regionA + 4 * SZ_ACT);
    bf16* g     = (bf16*)(regionA);   // 4096*3328*2 = 27.3 MB, reuses xn..attnb

    dim3 blk(256);

    // weight conversion
    convert4<<<dim3(1024, 4, 4), blk, 0, stream>>>(wq_w, wk_w, wv_w, wo_w, Wq, Wk, Wv, Wo);
    convert_w13<<<dim3(3328, 4, 2), blk, 0, stream>>>(w1_w, w3_w, W1p, W3p);
    convert_w2<<<dim3(1024, 13, 1), blk, 0, stream>>>(w2_w, W2p);

    // xn = rmsnorm(x, seq_norm_w)
    rmsnorm_in<<<4096, blk, 0, stream>>>(x, seq_norm_w, xn);

    // q/k/v projections with fused per-head rmsnorm on q,k
    gemm_qkv<<<dim3(32, 8, 3), blk, 0, stream>>>(xn, Wq, Wk, Wv, wq_b, wk_b, wv_b,
                                                 q_norm_w, k_norm_w, qb, kb, vb);

    // windowed causal attention
    attn_win<<<dim3(16, 16, 4), blk, 0, stream>>>(qb, kb, vb, winp, attnb);

    // output projection, split-K=2 -> f32 partials
    gemm_splitk<<<dim3(32, 8, 2), blk, 0, stream>>>(attnb, Wo, part, 1024, 1024, 512);

    // h = x + rmsnorm(p0+p1+wo_b, seq_post); hn = rmsnorm(h, ffn_norm)
    resid_norm<true><<<4096, blk, 0, stream>>>(x, part, part + 4096 * 1024, wo_b,
                                               seq_post_norm_w, ffn_norm_w, h, hn);

    // fused FFN1: g = silu(hn@W1^T+b1) * (hn@W3^T+b3)
    gemm_ffn1<<<dim3(32, 26, 1), blk, 0, stream>>>(hn, W1p, W3p, w1_b, w3_b, g);

    // FFN2: split-K=2 over K=3328 -> f32 partials
    gemm_splitk<<<dim3(32, 8, 2), blk, 0, stream>>>(g, W2p, part, 1024, 3328, 1664);

    // out = h + rmsnorm(p0+p1+w2_b, ffn_post)
    resid_norm<false><<<4096, blk, 0, stream>>>(h, part, part + 4096 * 1024, w2_b,
                                                ffn_post_norm_w, nullptr, out, nullptr);
}

// Round 3
// 399.918 us; speedup vs baseline: 1.2441x; 1.1744x over previous
//
#include <hip/hip_runtime.h>
#include <cmath>
#include <cstdint>

typedef __bf16 bf16;
typedef bf16 bf16x4 __attribute__((ext_vector_type(4)));
typedef bf16 bf16x8 __attribute__((ext_vector_type(8)));
typedef float f32x4 __attribute__((ext_vector_type(4)));
typedef unsigned int u32;
typedef u32 u32x4 __attribute__((ext_vector_type(4)));

#define EPS 1e-5f

__device__ __forceinline__ float clipf(float v) {
    return fminf(fmaxf(v, -10000.0f), 10000.0f);
}
__device__ __forceinline__ float fin0(float v) { return isfinite(v) ? v : 0.0f; }

__device__ __forceinline__ void async_copy16(void* lds, const void* g) {
    __builtin_amdgcn_global_load_lds((__attribute__((address_space(1))) void*)(void*)g,
                                     (__attribute__((address_space(3))) void*)lds,
                                     16, 0, 0);
}

// ---------------- weight converts (fp32 -> bf16, optional zero pad) ----------------
__global__ __launch_bounds__(256) void convert4(const float* __restrict__ i0, const float* __restrict__ i1,
                                                const float* __restrict__ i2, const float* __restrict__ i3,
                                                bf16* __restrict__ o0, bf16* __restrict__ o1,
                                                bf16* __restrict__ o2, bf16* __restrict__ o3) {
    int z = blockIdx.z;
    const float* in = (z == 0) ? i0 : (z == 1) ? i1 : (z == 2) ? i2 : i3;
    bf16* out = (z == 0) ? o0 : (z == 1) ? o1 : (z == 2) ? o2 : o3;
    int r = blockIdx.x;
    int c = blockIdx.y * 256 + threadIdx.x;
    out[(size_t)r * 1024 + c] = (bf16)in[(size_t)r * 1024 + c];
}

// w1/w3: rows 3280 -> 3328 (pad rows), cols 1024. grid (3328, 4, 2)
__global__ __launch_bounds__(256) void convert_w13(const float* __restrict__ i0, const float* __restrict__ i1,
                                                   bf16* __restrict__ o0, bf16* __restrict__ o1) {
    const float* in = blockIdx.z ? i1 : i0;
    bf16* out = blockIdx.z ? o1 : o0;
    int r = blockIdx.x;
    int c = blockIdx.y * 256 + threadIdx.x;
    float v = (r < 3280) ? in[(size_t)r * 1024 + c] : 0.0f;
    out[(size_t)r * 1024 + c] = (bf16)v;
}

// w2: 1024 x 3280 -> 1024 x 3328 (pad cols). grid (1024, 13)
__global__ __launch_bounds__(256) void convert_w2(const float* __restrict__ in, bf16* __restrict__ out) {
    int r = blockIdx.x;
    int c = blockIdx.y * 256 + threadIdx.x;
    float v = (c < 3280) ? in[(size_t)r * 3280 + c] : 0.0f;
    out[(size_t)r * 3328 + c] = (bf16)v;
}

// ---------------- block reduction helper (256 threads) ----------------
__device__ __forceinline__ float blockReduceSum(float v, float* sbuf) {
    #pragma unroll
    for (int off = 32; off >= 1; off >>= 1) v += __shfl_xor(v, off, 64);
    int w = threadIdx.x >> 6;
    __syncthreads();
    if ((threadIdx.x & 63) == 0) sbuf[w] = v;
    __syncthreads();
    return sbuf[0] + sbuf[1] + sbuf[2] + sbuf[3];
}

// ---------------- rmsnorm over D=1024, fp32 in -> bf16 out ----------------
__global__ __launch_bounds__(256) void rmsnorm_in(const float* __restrict__ x,
                                                  const float* __restrict__ w,
                                                  bf16* __restrict__ out) {
    __shared__ float sred[4];
    int row = blockIdx.x, t = threadIdx.x;
    f32x4 xv = ((const f32x4*)(x + (size_t)row * 1024))[t];
    f32x4 cv;
    cv[0] = clipf(xv[0]); cv[1] = clipf(xv[1]); cv[2] = clipf(xv[2]); cv[3] = clipf(xv[3]);
    float ss = cv[0]*cv[0] + cv[1]*cv[1] + cv[2]*cv[2] + cv[3]*cv[3];
    float tot = blockReduceSum(ss, sred);
    float rms = sqrtf(fmaxf(tot * (1.0f / 1024.0f), EPS) + EPS);
    f32x4 wv = ((const f32x4*)w)[t];
    bf16x4 o;
    o[0] = (bf16)fin0(cv[0] / rms * wv[0]);
    o[1] = (bf16)fin0(cv[1] / rms * wv[1]);
    o[2] = (bf16)fin0(cv[2] / rms * wv[2]);
    o[3] = (bf16)fin0(cv[3] / rms * wv[3]);
    *(bf16x4*)(out + (size_t)row * 1024 + t * 4) = o;
}

// ---------------- resid+norm: a = p0+p1+bias; h = x + rmsnorm(a, wpost); opt hn = rmsnorm(h, wnext) ----------------
template <bool EMIT>
__global__ __launch_bounds__(256) void resid_norm(const float* __restrict__ xres,
                                                  const float* __restrict__ p0,
                                                  const float* __restrict__ p1,
                                                  const float* __restrict__ bias,
                                                  const float* __restrict__ wpost,
                                                  const float* __restrict__ wnext,
                                                  float* __restrict__ hout,
                                                  bf16* __restrict__ hnout) {
    __shared__ float sred[4];
    int row = blockIdx.x, t = threadIdx.x;
    f32x4 a0 = ((const f32x4*)(p0 + (size_t)row * 1024))[t];
    f32x4 a1 = ((const f32x4*)(p1 + (size_t)row * 1024))[t];
    f32x4 bv = ((const f32x4*)bias)[t];
    f32x4 af;
    af[0] = clipf(a0[0] + a1[0] + bv[0]);
    af[1] = clipf(a0[1] + a1[1] + bv[1]);
    af[2] = clipf(a0[2] + a1[2] + bv[2]);
    af[3] = clipf(a0[3] + a1[3] + bv[3]);
    float ss = af[0]*af[0] + af[1]*af[1] + af[2]*af[2] + af[3]*af[3];
    float tot = blockReduceSum(ss, sred);
    float rms1 = sqrtf(fmaxf(tot * (1.0f / 1024.0f), EPS) + EPS);
    f32x4 xv = ((const f32x4*)(xres + (size_t)row * 1024))[t];
    f32x4 wp = ((const f32x4*)wpost)[t];
    f32x4 hv;
    hv[0] = xv[0] + fin0(af[0] / rms1 * wp[0]);
    hv[1] = xv[1] + fin0(af[1] / rms1 * wp[1]);
    hv[2] = xv[2] + fin0(af[2] / rms1 * wp[2]);
    hv[3] = xv[3] + fin0(af[3] / rms1 * wp[3]);
    ((f32x4*)(hout + (size_t)row * 1024))[t] = hv;
    if (EMIT) {
        f32x4 cv;
        cv[0] = clipf(hv[0]); cv[1] = clipf(hv[1]); cv[2] = clipf(hv[2]); cv[3] = clipf(hv[3]);
        float ss2 = cv[0]*cv[0] + cv[1]*cv[1] + cv[2]*cv[2] + cv[3]*cv[3];
        float tot2 = blockReduceSum(ss2, sred);
        float rms2 = sqrtf(fmaxf(tot2 * (1.0f / 1024.0f), EPS) + EPS);
        f32x4 wn = ((const f32x4*)wnext)[t];
        bf16x4 o;
        o[0] = (bf16)fin0(cv[0] / rms2 * wn[0]);
        o[1] = (bf16)fin0(cv[1] / rms2 * wn[1]);
        o[2] = (bf16)fin0(cv[2] / rms2 * wn[2]);
        o[3] = (bf16)fin0(cv[3] / rms2 * wn[3]);
        *(bf16x4*)(hnout + (size_t)row * 1024 + t * 4) = o;
    }
}

// ---------------- QKV GEMM with fused per-head rmsnorm (q,k) ----------------
// C[M,1024] = A[M,1024] @ B[1024,1024]^T + bias; z in {q,k,v}. grid (M/128, 8, 3)
__global__ __launch_bounds__(256) void gemm_qkv(const bf16* __restrict__ A,
                                                const bf16* __restrict__ B0,
                                                const bf16* __restrict__ B1,
                                                const bf16* __restrict__ B2,
                                                const float* __restrict__ g0,
                                                const float* __restrict__ g1,
                                                const float* __restrict__ g2,
                                                const float* __restrict__ qnw,
                                                const float* __restrict__ knw,
                                                bf16* __restrict__ C0,
                                                bf16* __restrict__ C1,
                                                bf16* __restrict__ C2) {
    const int z = blockIdx.z;
    const bf16* B = (z == 0) ? B0 : (z == 1) ? B1 : B2;
    const float* bias = (z == 0) ? g0 : (z == 1) ? g1 : g2;
    bf16* C = (z == 0) ? C0 : (z == 1) ? C1 : C2;
    const float* hw = (z == 0) ? qnw : knw;

    __shared__ __align__(16) bf16 sA[128 * 32];
    __shared__ __align__(16) bf16 sB[128 * 32];
    const int tid = threadIdx.x;
    const int w = tid >> 6, lane = tid & 63;
    const int m0 = blockIdx.x * 128;
    const int n0 = blockIdx.y * 128;
    const int mwo = (w >> 1) * 64, nwo = (w & 1) * 64;
    const int r16 = lane & 15, quad = lane >> 4;
    const int kreg = quad * 8;
    const int K = 1024, N = 1024;

    f32x4 zero = {0.f, 0.f, 0.f, 0.f};
    f32x4 acc[4][4];
    #pragma unroll
    for (int i = 0; i < 4; ++i)
        #pragma unroll
        for (int j = 0; j < 4; ++j) acc[i][j] = zero;

    const int c0 = tid, c1 = tid + 256;
    const int am0 = c0 >> 2, ak0 = (c0 & 3) << 3;
    const int am1 = c1 >> 2, ak1 = (c1 & 3) << 3;

    for (int kt = 0; kt < 32; ++kt) {
        const int kb = kt << 5;
        __syncthreads();
        async_copy16(&sA[c0 * 8], &A[(size_t)(m0 + am0) * K + kb + ak0]);
        async_copy16(&sA[c1 * 8], &A[(size_t)(m0 + am1) * K + kb + ak1]);
        async_copy16(&sB[c0 * 8], &B[(size_t)(n0 + am0) * K + kb + ak0]);
        async_copy16(&sB[c1 * 8], &B[(size_t)(n0 + am1) * K + kb + ak1]);
        __syncthreads();

        bf16x8 af[4], bfr[4];
        #pragma unroll
        for (int i = 0; i < 4; ++i)
            af[i] = *(const bf16x8*)&sA[(mwo + i * 16 + r16) * 32 + kreg];
        #pragma unroll
        for (int i = 0; i < 4; ++i)
            bfr[i] = *(const bf16x8*)&sB[(nwo + i * 16 + r16) * 32 + kreg];
        #pragma unroll
        for (int mi = 0; mi < 4; ++mi)
            #pragma unroll
            for (int ni = 0; ni < 4; ++ni)
                acc[mi][ni] = __builtin_amdgcn_mfma_f32_16x16x32_bf16(af[mi], bfr[ni], acc[mi][ni], 0, 0, 0);
    }

    float bv[4], nwv[4];
    #pragma unroll
    for (int ni = 0; ni < 4; ++ni) {
        int col = n0 + nwo + ni * 16 + r16;
        bv[ni] = bias[col];
        nwv[ni] = (z < 2) ? hw[ni * 16 + r16] : 0.0f;  // col % 64 == ni*16 + r16
    }

    if (z < 2) {
        // fused per-head rmsnorm: each wave tile spans exactly one 64-wide head
        #pragma unroll
        for (int mi = 0; mi < 4; ++mi) {
            #pragma unroll
            for (int r = 0; r < 4; ++r) {
                float v[4], ss = 0.0f;
                #pragma unroll
                for (int ni = 0; ni < 4; ++ni) {
                    v[ni] = clipf(acc[mi][ni][r] + bv[ni]);
                    ss += v[ni] * v[ni];
                }
                ss += __shfl_xor(ss, 1, 64);
                ss += __shfl_xor(ss, 2, 64);
                ss += __shfl_xor(ss, 4, 64);
                ss += __shfl_xor(ss, 8, 64);
                float rms = sqrtf(fmaxf(ss * (1.0f / 64.0f), EPS) + EPS);
                int row = m0 + mwo + mi * 16 + quad * 4 + r;
                #pragma unroll
                for (int ni = 0; ni < 4; ++ni) {
                    int col = n0 + nwo + ni * 16 + r16;
                    C[(size_t)row * N + col] = (bf16)fin0(v[ni] / rms * nwv[ni]);
                }
            }
        }
    } else {
        #pragma unroll
        for (int mi = 0; mi < 4; ++mi)
            #pragma unroll
            for (int ni = 0; ni < 4; ++ni) {
                int col = n0 + nwo + ni * 16 + r16;
                #pragma unroll
                for (int r = 0; r < 4; ++r) {
                    int row = m0 + mwo + mi * 16 + quad * 4 + r;
                    C[(size_t)row * N + col] = (bf16)(acc[mi][ni][r] + bv[ni]);
                }
            }
    }
}

// ---------------- fused FFN1: g = silu(A@W1^T + b1) * (A@W3^T + b3) ----------------
// A[M,1024], W1/W3[3328,1024], g[M,3328]. grid (M/128, 26), block 512.
// 8 waves in 2x4: per-wave 64x32 per stream -> acc 16 f32x4 total (reg-pressure fix vs r2).
__global__ __launch_bounds__(512) void gemm_ffn1(const bf16* __restrict__ A,
                                                 const bf16* __restrict__ B1,
                                                 const bf16* __restrict__ B3,
                                                 const float* __restrict__ b1,
                                                 const float* __restrict__ b3,
                                                 bf16* __restrict__ G) {
    __shared__ __align__(16) bf16 sA[128 * 32];
    __shared__ __align__(16) bf16 sB1[128 * 32];
    __shared__ __align__(16) bf16 sB3[128 * 32];
    const int tid = threadIdx.x;
    const int w = tid >> 6, lane = tid & 63;
    const int m0 = blockIdx.x * 128;
    const int n0 = blockIdx.y * 128;
    const int mwo = (w >> 2) * 64, nwo = (w & 3) * 32;
    const int r16 = lane & 15, quad = lane >> 4;
    const int kreg = quad * 8;
    const int K = 1024, N = 3328;

    f32x4 zero = {0.f, 0.f, 0.f, 0.f};
    f32x4 acc1[4][2], acc3[4][2];
    #pragma unroll
    for (int i = 0; i < 4; ++i)
        #pragma unroll
        for (int j = 0; j < 2; ++j) { acc1[i][j] = zero; acc3[i][j] = zero; }

    const int arow = tid >> 2, akoff = (tid & 3) << 3;

    for (int kt = 0; kt < 32; ++kt) {
        const int kb = kt << 5;
        __syncthreads();
        async_copy16(&sA[tid * 8],  &A[(size_t)(m0 + arow) * K + kb + akoff]);
        async_copy16(&sB1[tid * 8], &B1[(size_t)(n0 + arow) * K + kb + akoff]);
        async_copy16(&sB3[tid * 8], &B3[(size_t)(n0 + arow) * K + kb + akoff]);
        __syncthreads();

        bf16x8 af[4], bf1[2], bf3[2];
        #pragma unroll
        for (int i = 0; i < 4; ++i)
            af[i]  = *(const bf16x8*)&sA[(mwo + i * 16 + r16) * 32 + kreg];
        #pragma unroll
        for (int i = 0; i < 2; ++i) {
            bf1[i] = *(const bf16x8*)&sB1[(nwo + i * 16 + r16) * 32 + kreg];
            bf3[i] = *(const bf16x8*)&sB3[(nwo + i * 16 + r16) * 32 + kreg];
        }
        #pragma unroll
        for (int mi = 0; mi < 4; ++mi)
            #pragma unroll
            for (int ni = 0; ni < 2; ++ni) {
                acc1[mi][ni] = __builtin_amdgcn_mfma_f32_16x16x32_bf16(af[mi], bf1[ni], acc1[mi][ni], 0, 0, 0);
                acc3[mi][ni] = __builtin_amdgcn_mfma_f32_16x16x32_bf16(af[mi], bf3[ni], acc3[mi][ni], 0, 0, 0);
            }
    }

    #pragma unroll
    for (int ni = 0; ni < 2; ++ni) {
        int col = n0 + nwo + ni * 16 + r16;
        float bv1 = (col < 3280) ? b1[col] : 0.0f;
        float bv3 = (col < 3280) ? b3[col] : 0.0f;
        #pragma unroll
        for (int mi = 0; mi < 4; ++mi) {
            #pragma unroll
            for (int r = 0; r < 4; ++r) {
                int row = m0 + mwo + mi * 16 + quad * 4 + r;
                float z1 = acc1[mi][ni][r] + bv1;
                float z3 = acc3[mi][ni][r] + bv3;
                float s = z1 / (1.0f + __expf(-z1));
                G[(size_t)row * N + col] = (bf16)(s * z3);
            }
        }
    }
}

// ---------------- split-K GEMM -> f32 partials (no bias) ----------------
// P[s][M][N] = A[M, s*Kh : (s+1)*Kh] @ B[N, ...]^T. grid (M/128, N/128, 2)
__global__ __launch_bounds__(256) void gemm_splitk(const bf16* __restrict__ A,
                                                   const bf16* __restrict__ B,
                                                   float* __restrict__ P,
                                                   int N, int K, int Kh) {
    const int s = blockIdx.z;
    __shared__ __align__(16) bf16 sA[128 * 32];
    __shared__ __align__(16) bf16 sB[128 * 32];
    const int tid = threadIdx.x;
    const int w = tid >> 6, lane = tid & 63;
    const int m0 = blockIdx.x * 128;
    const int n0 = blockIdx.y * 128;
    const int mwo = (w >> 1) * 64, nwo = (w & 1) * 64;
    const int r16 = lane & 15, quad = lane >> 4;
    const int kreg = quad * 8;
    const int kbase = s * Kh;

    f32x4 zero = {0.f, 0.f, 0.f, 0.f};
    f32x4 acc[4][4];
    #pragma unroll
    for (int i = 0; i < 4; ++i)
        #pragma unroll
        for (int j = 0; j < 4; ++j) acc[i][j] = zero;

    const int c0 = tid, c1 = tid + 256;
    const int am0 = c0 >> 2, ak0 = (c0 & 3) << 3;
    const int am1 = c1 >> 2, ak1 = (c1 & 3) << 3;
    const int kIters = Kh >> 5;

    for (int kt = 0; kt < kIters; ++kt) {
        const int kb = kbase + (kt << 5);
        __syncthreads();
        async_copy16(&sA[c0 * 8], &A[(size_t)(m0 + am0) * K + kb + ak0]);
        async_copy16(&sA[c1 * 8], &A[(size_t)(m0 + am1) * K + kb + ak1]);
        async_copy16(&sB[c0 * 8], &B[(size_t)(n0 + am0) * K + kb + ak0]);
        async_copy16(&sB[c1 * 8], &B[(size_t)(n0 + am1) * K + kb + ak1]);
        __syncthreads();

        bf16x8 af[4], bfr[4];
        #pragma unroll
        for (int i = 0; i < 4; ++i) {
            af[i]  = *(const bf16x8*)&sA[(mwo + i * 16 + r16) * 32 + kreg];
            bfr[i] = *(const bf16x8*)&sB[(nwo + i * 16 + r16) * 32 + kreg];
        }
        #pragma unroll
        for (int mi = 0; mi < 4; ++mi)
            #pragma unroll
            for (int ni = 0; ni < 4; ++ni)
                acc[mi][ni] = __builtin_amdgcn_mfma_f32_16x16x32_bf16(af[mi], bfr[ni], acc[mi][ni], 0, 0, 0);
    }

    float* Pz = P + (size_t)s * 4096 * 1024;
    #pragma unroll
    for (int mi = 0; mi < 4; ++mi)
        #pragma unroll
        for (int ni = 0; ni < 4; ++ni) {
            int col = n0 + nwo + ni * 16 + r16;
            #pragma unroll
            for (int r = 0; r < 4; ++r) {
                int row = m0 + mwo + mi * 16 + quad * 4 + r;
                Pz[(size_t)row * N + col] = acc[mi][ni][r];
            }
        }
}

// ---------------- windowed causal flash attention ----------------
// grid: (L/64, H, B), block 256. q/k/v laid out (B, L, H, 64) bf16.
__global__ __launch_bounds__(256) void attn_win(const bf16* __restrict__ q,
                                                const bf16* __restrict__ k,
                                                const bf16* __restrict__ v,
                                                const int* __restrict__ winp,
                                                bf16* __restrict__ o) {
    __shared__ __align__(16) bf16 sQ[64 * 64];
    __shared__ __align__(16) bf16 sK[64 * 64];
    __shared__ __align__(16) bf16 sVt[64 * 72];
    __shared__ __align__(16) bf16 sP[64 * 64];
    const int tid = threadIdx.x, w = tid >> 6, lane = tid & 63;
    const int qt = blockIdx.x, h = blockIdx.y, b = blockIdx.z;
    const int q0 = qt * 64;
    const int win = *winp;
    const float scale = 0.125f;  // 64^-0.5
    const int r16 = lane & 15, quad = lane >> 4;

    for (int c = tid; c < 512; c += 256) {
        int qr = c >> 3, col = (c & 7) * 8;
        *(u32x4*)&sQ[qr * 64 + col] =
            *(const u32x4*)&q[(((size_t)b * 1024 + q0 + qr) * 16 + h) * 64 + col];
    }
    __syncthreads();
    bf16x8 aq0 = *(const bf16x8*)&sQ[(w * 16 + r16) * 64 + quad * 8];
    bf16x8 aq1 = *(const bf16x8*)&sQ[(w * 16 + r16) * 64 + 32 + quad * 8];

    float M[4], Lr[4];
    f32x4 zero = {0.f, 0.f, 0.f, 0.f};
    f32x4 accO[4];
    #pragma unroll
    for (int r = 0; r < 4; ++r) { M[r] = -INFINITY; Lr[r] = 0.0f; }
    #pragma unroll
    for (int nf = 0; nf < 4; ++nf) accO[nf] = zero;

    int lo = q0 - (win - 1); if (lo < 0) lo = 0;
    const int kt0 = lo >> 6;

    for (int kt = kt0; kt <= qt; ++kt) {
        __syncthreads();
        for (int c = tid; c < 512; c += 256) {
            int kr = c >> 3, col = (c & 7) * 8;
            *(u32x4*)&sK[kr * 64 + col] =
                *(const u32x4*)&k[(((size_t)b * 1024 + kt * 64 + kr) * 16 + h) * 64 + col];
        }
        for (int e = tid; e < 4096; e += 256) {
            int key = e >> 6, hd = e & 63;
            sVt[hd * 72 + key] = v[(((size_t)b * 1024 + kt * 64 + key) * 16 + h) * 64 + hd];
        }
        __syncthreads();

        f32x4 sf[4];
        #pragma unroll
        for (int nf = 0; nf < 4; ++nf) {
            bf16x8 bk0 = *(const bf16x8*)&sK[(nf * 16 + r16) * 64 + quad * 8];
            bf16x8 bk1 = *(const bf16x8*)&sK[(nf * 16 + r16) * 64 + 32 + quad * 8];
            f32x4 accS = zero;
            accS = __builtin_amdgcn_mfma_f32_16x16x32_bf16(aq0, bk0, accS, 0, 0, 0);
            accS = __builtin_amdgcn_mfma_f32_16x16x32_bf16(aq1, bk1, accS, 0, 0, 0);
            sf[nf] = accS;
        }

        #pragma unroll
        for (int r = 0; r < 4; ++r) {
            int i = q0 + w * 16 + quad * 4 + r;
            float p[4];
            float rowmax = -INFINITY;
            #pragma unroll
            for (int nf = 0; nf < 4; ++nf) {
                int j = kt * 64 + nf * 16 + r16;
                bool ok = (j <= i) && (i - j < win);
                float sv = ok ? sf[nf][r] * scale : -INFINITY;
                p[nf] = sv;
                rowmax = fmaxf(rowmax, sv);
            }
            #pragma unroll
            for (int off = 1; off < 16; off <<= 1)
                rowmax = fmaxf(rowmax, __shfl_xor(rowmax, off, 64));
            float mnew = fmaxf(M[r], rowmax);
            float alpha = (mnew == M[r]) ? 1.0f : __expf(M[r] - mnew);
            float rs = 0.0f;
            #pragma unroll
            for (int nf = 0; nf < 4; ++nf) {
                float pv = (p[nf] == -INFINITY) ? 0.0f : __expf(p[nf] - mnew);
                rs += pv;
                sP[(w * 16 + quad * 4 + r) * 64 + nf * 16 + r16] = (bf16)pv;
            }
            #pragma unroll
            for (int off = 1; off < 16; off <<= 1) rs += __shfl_xor(rs, off, 64);
            Lr[r] = Lr[r] * alpha + rs;
            M[r] = mnew;
            #pragma unroll
            for (int nf = 0; nf < 4; ++nf) accO[nf][r] = accO[nf][r] * alpha;
        }
        __syncthreads();

        bf16x8 ap0 = *(const bf16x8*)&sP[(w * 16 + r16) * 64 + quad * 8];
        bf16x8 ap1 = *(const bf16x8*)&sP[(w * 16 + r16) * 64 + 32 + quad * 8];
        #pragma unroll
        for (int nf = 0; nf < 4; ++nf) {
            bf16x8 bv0 = *(const bf16x8*)&sVt[(nf * 16 + r16) * 72 + quad * 8];
            bf16x8 bv1 = *(const bf16x8*)&sVt[(nf * 16 + r16) * 72 + 32 + quad * 8];
            accO[nf] = __builtin_amdgcn_mfma_f32_16x16x32_bf16(ap0, bv0, accO[nf], 0, 0, 0);
            accO[nf] = __builtin_amdgcn_mfma_f32_16x16x32_bf16(ap1, bv1, accO[nf], 0, 0, 0);
        }
    }

    #pragma unroll
    for (int r = 0; r < 4; ++r) {
        float inv = (Lr[r] > 0.0f) ? 1.0f / Lr[r] : 0.0f;
        int row = q0 + w * 16 + quad * 4 + r;
        #pragma unroll
        for (int nf = 0; nf < 4; ++nf) {
            float ov = fin0(accO[nf][r] * inv);
            o[(((size_t)b * 1024 + row) * 16 + h) * 64 + nf * 16 + r16] = (bf16)ov;
        }
    }
}

extern "C" void kernel_launch(void* const* d_in, const int* in_sizes, int n_in,
                              void* d_out, int out_size, void* d_ws, size_t ws_size,
                              hipStream_t stream) {
    const float* x       = (const float*)d_in[0];
    const float* wq_w    = (const float*)d_in[1];
    const float* wq_b    = (const float*)d_in[2];
    const float* wk_w    = (const float*)d_in[3];
    const float* wk_b    = (const float*)d_in[4];
    const float* wv_w    = (const float*)d_in[5];
    const float* wv_b    = (const float*)d_in[6];
    const float* wo_w    = (const float*)d_in[7];
    const float* wo_b    = (const float*)d_in[8];
    const float* q_norm_w= (const float*)d_in[9];
    const float* k_norm_w= (const float*)d_in[10];
    const float* seq_norm_w      = (const float*)d_in[11];
    const float* seq_post_norm_w = (const float*)d_in[12];
    const float* ffn_norm_w      = (const float*)d_in[13];
    const float* ffn_post_norm_w = (const float*)d_in[14];
    const float* w1_w    = (const float*)d_in[15];
    const float* w1_b    = (const float*)d_in[16];
    const float* w2_w    = (const float*)d_in[17];
    const float* w2_b    = (const float*)d_in[18];
    const float* w3_w    = (const float*)d_in[19];
    const float* w3_b    = (const float*)d_in[20];
    const int*   winp    = (const int*)d_in[21];
    float* out = (float*)d_out;

    const size_t SZ_W   = 2097152;    // 1024*1024*2
    const size_t SZ_WP  = 6815744;    // 3328*1024*2
    const size_t SZ_ACT = 8388608;    // 4096*1024*2
    const size_t SZ_H   = 16777216;   // 4096*1024*4
    const size_t SZ_P   = 33554432;   // 2*4096*1024*4

    char* p = (char*)d_ws;
    bf16* Wq  = (bf16*)p; p += SZ_W;
    bf16* Wk  = (bf16*)p; p += SZ_W;
    bf16* Wv  = (bf16*)p; p += SZ_W;
    bf16* Wo  = (bf16*)p; p += SZ_W;
    bf16* W1p = (bf16*)p; p += SZ_WP;
    bf16* W3p = (bf16*)p; p += SZ_WP;
    bf16* W2p = (bf16*)p; p += SZ_WP;
    float* h  = (float*)p; p += SZ_H;
    bf16* hn  = (bf16*)p; p += SZ_ACT;
    float* part = (float*)p; p += SZ_P;   // split-K partials (O-proj, then FFN2)
    char* regionA = p;  // aliased: attn-phase buffers, later g
    bf16* xn    = (bf16*)(regionA);
    bf16* qb    = (bf16*)(regionA + 1 * SZ_ACT);
    bf16* kb    = (bf16*)(regionA + 2 * SZ_ACT);
    bf16* vb    = (bf16*)(regionA + 3 * SZ_ACT);
    bf16* attnb = (bf16*)(regionA + 4 * SZ_ACT);
    bf16* g     = (bf16*)(regionA);   // 4096*3328*2 = 27.3 MB, reuses xn..attnb

    dim3 blk(256);

    // weight conversion
    convert4<<<dim3(1024, 4, 4), blk, 0, stream>>>(wq_w, wk_w, wv_w, wo_w, Wq, Wk, Wv, Wo);
    convert_w13<<<dim3(3328, 4, 2), blk, 0, stream>>>(w1_w, w3_w, W1p, W3p);
    convert_w2<<<dim3(1024, 13, 1), blk, 0, stream>>>(w2_w, W2p);

    // xn = rmsnorm(x, seq_norm_w)
    rmsnorm_in<<<4096, blk, 0, stream>>>(x, seq_norm_w, xn);

    // q/k/v projections with fused per-head rmsnorm on q,k
    gemm_qkv<<<dim3(32, 8, 3), blk, 0, stream>>>(xn, Wq, Wk, Wv, wq_b, wk_b, wv_b,
                                                 q_norm_w, k_norm_w, qb, kb, vb);

    // windowed causal attention
    attn_win<<<dim3(16, 16, 4), blk, 0, stream>>>(qb, kb, vb, winp, attnb);

    // output projection, split-K=2 -> f32 partials
    gemm_splitk<<<dim3(32, 8, 2), blk, 0, stream>>>(attnb, Wo, part, 1024, 1024, 512);

    // h = x + rmsnorm(p0+p1+wo_b, seq_post); hn = rmsnorm(h, ffn_norm)
    resid_norm<true><<<4096, blk, 0, stream>>>(x, part, part + 4096 * 1024, wo_b,
                                               seq_post_norm_w, ffn_norm_w, h, hn);

    // fused FFN1: g = silu(hn@W1^T+b1) * (hn@W3^T+b3), 512-thread blocks
    gemm_ffn1<<<dim3(32, 26), dim3(512), 0, stream>>>(hn, W1p, W3p, w1_b, w3_b, g);

    // FFN2: split-K=2 over K=3328 -> f32 partials
    gemm_splitk<<<dim3(32, 8, 2), blk, 0, stream>>>(g, W2p, part, 1024, 3328, 1664);

    // out = h + rmsnorm(p0+p1+w2_b, ffn_post)
    resid_norm<false><<<4096, blk, 0, stream>>>(h, part, part + 4096 * 1024, w2_b,
                                                ffn_post_norm_w, nullptr, out, nullptr);
}

// Round 4
// 381.988 us; speedup vs baseline: 1.3024x; 1.0469x over previous
//
#include <hip/hip_runtime.h>
#include <cmath>
#include <cstdint>

typedef __bf16 bf16;
typedef bf16 bf16x4 __attribute__((ext_vector_type(4)));
typedef bf16 bf16x8 __attribute__((ext_vector_type(8)));
typedef float f32x4 __attribute__((ext_vector_type(4)));
typedef unsigned int u32;
typedef u32 u32x4 __attribute__((ext_vector_type(4)));

#define EPS 1e-5f

__device__ __forceinline__ float clipf(float v) {
    return fminf(fmaxf(v, -10000.0f), 10000.0f);
}
__device__ __forceinline__ float fin0(float v) { return isfinite(v) ? v : 0.0f; }

__device__ __forceinline__ void async_copy16(void* lds, const void* g) {
    __builtin_amdgcn_global_load_lds((__attribute__((address_space(1))) void*)(void*)g,
                                     (__attribute__((address_space(3))) void*)lds,
                                     16, 0, 0);
}

// ---------------- weight converts (fp32 -> bf16, optional zero pad), 4-wide ----------------
// grid (1024, 1, 4), 256 thr * 4 elems = 1024 cols
__global__ __launch_bounds__(256) void convert4(const float* __restrict__ i0, const float* __restrict__ i1,
                                                const float* __restrict__ i2, const float* __restrict__ i3,
                                                bf16* __restrict__ o0, bf16* __restrict__ o1,
                                                bf16* __restrict__ o2, bf16* __restrict__ o3) {
    int z = blockIdx.z;
    const float* in = (z == 0) ? i0 : (z == 1) ? i1 : (z == 2) ? i2 : i3;
    bf16* out = (z == 0) ? o0 : (z == 1) ? o1 : (z == 2) ? o2 : o3;
    int r = blockIdx.x;
    f32x4 v = ((const f32x4*)(in + (size_t)r * 1024))[threadIdx.x];
    bf16x4 o = {(bf16)v[0], (bf16)v[1], (bf16)v[2], (bf16)v[3]};
    ((bf16x4*)(out + (size_t)r * 1024))[threadIdx.x] = o;
}

// w1/w3: rows 3280 -> 3328 (pad rows), cols 1024. grid (3328, 1, 2)
__global__ __launch_bounds__(256) void convert_w13(const float* __restrict__ i0, const float* __restrict__ i1,
                                                   bf16* __restrict__ o0, bf16* __restrict__ o1) {
    const float* in = blockIdx.z ? i1 : i0;
    bf16* out = blockIdx.z ? o1 : o0;
    int r = blockIdx.x;
    bf16x4 o = {(bf16)0.f, (bf16)0.f, (bf16)0.f, (bf16)0.f};
    if (r < 3280) {
        f32x4 v = ((const f32x4*)(in + (size_t)r * 1024))[threadIdx.x];
        o[0] = (bf16)v[0]; o[1] = (bf16)v[1]; o[2] = (bf16)v[2]; o[3] = (bf16)v[3];
    }
    ((bf16x4*)(out + (size_t)r * 1024))[threadIdx.x] = o;
}

// w2: 1024 x 3280 -> 1024 x 3328 (pad cols). grid (1024, 4)
__global__ __launch_bounds__(256) void convert_w2(const float* __restrict__ in, bf16* __restrict__ out) {
    int r = blockIdx.x;
    int c4 = (blockIdx.y * 256 + threadIdx.x) * 4;
    if (c4 >= 3328) return;
    bf16x4 o = {(bf16)0.f, (bf16)0.f, (bf16)0.f, (bf16)0.f};
    if (c4 + 3 < 3280) {
        f32x4 v = *(const f32x4*)(in + (size_t)r * 3280 + c4);
        o[0] = (bf16)v[0]; o[1] = (bf16)v[1]; o[2] = (bf16)v[2]; o[3] = (bf16)v[3];
    } else {
        #pragma unroll
        for (int j = 0; j < 4; ++j)
            if (c4 + j < 3280) o[j] = (bf16)in[(size_t)r * 3280 + c4 + j];
    }
    *(bf16x4*)(out + (size_t)r * 3328 + c4) = o;
}

// ---------------- block reduction helper (256 threads) ----------------
__device__ __forceinline__ float blockReduceSum(float v, float* sbuf) {
    #pragma unroll
    for (int off = 32; off >= 1; off >>= 1) v += __shfl_xor(v, off, 64);
    int w = threadIdx.x >> 6;
    __syncthreads();
    if ((threadIdx.x & 63) == 0) sbuf[w] = v;
    __syncthreads();
    return sbuf[0] + sbuf[1] + sbuf[2] + sbuf[3];
}

// ---------------- rmsnorm over D=1024, fp32 in -> bf16 out ----------------
__global__ __launch_bounds__(256) void rmsnorm_in(const float* __restrict__ x,
                                                  const float* __restrict__ w,
                                                  bf16* __restrict__ out) {
    __shared__ float sred[4];
    int row = blockIdx.x, t = threadIdx.x;
    f32x4 xv = ((const f32x4*)(x + (size_t)row * 1024))[t];
    f32x4 cv;
    cv[0] = clipf(xv[0]); cv[1] = clipf(xv[1]); cv[2] = clipf(xv[2]); cv[3] = clipf(xv[3]);
    float ss = cv[0]*cv[0] + cv[1]*cv[1] + cv[2]*cv[2] + cv[3]*cv[3];
    float tot = blockReduceSum(ss, sred);
    float rms = sqrtf(fmaxf(tot * (1.0f / 1024.0f), EPS) + EPS);
    f32x4 wv = ((const f32x4*)w)[t];
    bf16x4 o;
    o[0] = (bf16)fin0(cv[0] / rms * wv[0]);
    o[1] = (bf16)fin0(cv[1] / rms * wv[1]);
    o[2] = (bf16)fin0(cv[2] / rms * wv[2]);
    o[3] = (bf16)fin0(cv[3] / rms * wv[3]);
    *(bf16x4*)(out + (size_t)row * 1024 + t * 4) = o;
}

// ---------------- resid+norm: a = p0+p1+bias; h = x + rmsnorm(a, wpost); opt hn = rmsnorm(h, wnext) ----------------
template <bool EMIT>
__global__ __launch_bounds__(256) void resid_norm(const float* __restrict__ xres,
                                                  const float* __restrict__ p0,
                                                  const float* __restrict__ p1,
                                                  const float* __restrict__ bias,
                                                  const float* __restrict__ wpost,
                                                  const float* __restrict__ wnext,
                                                  float* __restrict__ hout,
                                                  bf16* __restrict__ hnout) {
    __shared__ float sred[4];
    int row = blockIdx.x, t = threadIdx.x;
    f32x4 a0 = ((const f32x4*)(p0 + (size_t)row * 1024))[t];
    f32x4 a1 = ((const f32x4*)(p1 + (size_t)row * 1024))[t];
    f32x4 bv = ((const f32x4*)bias)[t];
    f32x4 af;
    af[0] = clipf(a0[0] + a1[0] + bv[0]);
    af[1] = clipf(a0[1] + a1[1] + bv[1]);
    af[2] = clipf(a0[2] + a1[2] + bv[2]);
    af[3] = clipf(a0[3] + a1[3] + bv[3]);
    float ss = af[0]*af[0] + af[1]*af[1] + af[2]*af[2] + af[3]*af[3];
    float tot = blockReduceSum(ss, sred);
    float rms1 = sqrtf(fmaxf(tot * (1.0f / 1024.0f), EPS) + EPS);
    f32x4 xv = ((const f32x4*)(xres + (size_t)row * 1024))[t];
    f32x4 wp = ((const f32x4*)wpost)[t];
    f32x4 hv;
    hv[0] = xv[0] + fin0(af[0] / rms1 * wp[0]);
    hv[1] = xv[1] + fin0(af[1] / rms1 * wp[1]);
    hv[2] = xv[2] + fin0(af[2] / rms1 * wp[2]);
    hv[3] = xv[3] + fin0(af[3] / rms1 * wp[3]);
    ((f32x4*)(hout + (size_t)row * 1024))[t] = hv;
    if (EMIT) {
        f32x4 cv;
        cv[0] = clipf(hv[0]); cv[1] = clipf(hv[1]); cv[2] = clipf(hv[2]); cv[3] = clipf(hv[3]);
        float ss2 = cv[0]*cv[0] + cv[1]*cv[1] + cv[2]*cv[2] + cv[3]*cv[3];
        float tot2 = blockReduceSum(ss2, sred);
        float rms2 = sqrtf(fmaxf(tot2 * (1.0f / 1024.0f), EPS) + EPS);
        f32x4 wn = ((const f32x4*)wnext)[t];
        bf16x4 o;
        o[0] = (bf16)fin0(cv[0] / rms2 * wn[0]);
        o[1] = (bf16)fin0(cv[1] / rms2 * wn[1]);
        o[2] = (bf16)fin0(cv[2] / rms2 * wn[2]);
        o[3] = (bf16)fin0(cv[3] / rms2 * wn[3]);
        *(bf16x4*)(hnout + (size_t)row * 1024 + t * 4) = o;
    }
}

// ---------------- QKV GEMM, double-buffered, fused per-head rmsnorm (q,k), vT epilogue (v) ----------------
// grid (M/128, 8, 3), block 256.
__global__ __launch_bounds__(256) void gemm_qkv(const bf16* __restrict__ A,
                                                const bf16* __restrict__ B0,
                                                const bf16* __restrict__ B1,
                                                const bf16* __restrict__ B2,
                                                const float* __restrict__ g0,
                                                const float* __restrict__ g1,
                                                const float* __restrict__ g2,
                                                const float* __restrict__ qnw,
                                                const float* __restrict__ knw,
                                                bf16* __restrict__ C0,
                                                bf16* __restrict__ C1,
                                                bf16* __restrict__ VT) {
    const int z = blockIdx.z;
    const bf16* B = (z == 0) ? B0 : (z == 1) ? B1 : B2;
    const float* bias = (z == 0) ? g0 : (z == 1) ? g1 : g2;
    const float* hw = (z == 0) ? qnw : knw;

    __shared__ __align__(16) bf16 sA[2][128 * 32];
    __shared__ __align__(16) bf16 sB[2][128 * 32];
    const int tid = threadIdx.x;
    const int w = tid >> 6, lane = tid & 63;
    const int m0 = blockIdx.x * 128;
    const int n0 = blockIdx.y * 128;
    const int mwo = (w >> 1) * 64, nwo = (w & 1) * 64;
    const int r16 = lane & 15, quad = lane >> 4;
    const int kreg = quad * 8;
    const int K = 1024, N = 1024;

    f32x4 zero = {0.f, 0.f, 0.f, 0.f};
    f32x4 acc[4][4];
    #pragma unroll
    for (int i = 0; i < 4; ++i)
        #pragma unroll
        for (int j = 0; j < 4; ++j) acc[i][j] = zero;

    const int c0 = tid, c1 = tid + 256;
    const int am0 = c0 >> 2, ak0 = (c0 & 3) << 3;
    const int am1 = c1 >> 2, ak1 = (c1 & 3) << 3;

    // prologue stage into buf 0
    {
        async_copy16(&sA[0][c0 * 8], &A[(size_t)(m0 + am0) * K + ak0]);
        async_copy16(&sA[0][c1 * 8], &A[(size_t)(m0 + am1) * K + ak1]);
        async_copy16(&sB[0][c0 * 8], &B[(size_t)(n0 + am0) * K + ak0]);
        async_copy16(&sB[0][c1 * 8], &B[(size_t)(n0 + am1) * K + ak1]);
    }
    for (int kt = 0; kt < 32; ++kt) {
        __syncthreads();   // drains vmcnt for current buf; ds_reads of other buf already complete
        const int cur = kt & 1, nxt = cur ^ 1;
        if (kt + 1 < 32) {
            const int kb = (kt + 1) << 5;
            async_copy16(&sA[nxt][c0 * 8], &A[(size_t)(m0 + am0) * K + kb + ak0]);
            async_copy16(&sA[nxt][c1 * 8], &A[(size_t)(m0 + am1) * K + kb + ak1]);
            async_copy16(&sB[nxt][c0 * 8], &B[(size_t)(n0 + am0) * K + kb + ak0]);
            async_copy16(&sB[nxt][c1 * 8], &B[(size_t)(n0 + am1) * K + kb + ak1]);
        }
        bf16x8 af[4], bfr[4];
        #pragma unroll
        for (int i = 0; i < 4; ++i) {
            af[i]  = *(const bf16x8*)&sA[cur][(mwo + i * 16 + r16) * 32 + kreg];
            bfr[i] = *(const bf16x8*)&sB[cur][(nwo + i * 16 + r16) * 32 + kreg];
        }
        #pragma unroll
        for (int mi = 0; mi < 4; ++mi)
            #pragma unroll
            for (int ni = 0; ni < 4; ++ni)
                acc[mi][ni] = __builtin_amdgcn_mfma_f32_16x16x32_bf16(af[mi], bfr[ni], acc[mi][ni], 0, 0, 0);
    }

    float bv[4];
    #pragma unroll
    for (int ni = 0; ni < 4; ++ni) bv[ni] = bias[n0 + nwo + ni * 16 + r16];

    if (z < 2) {
        bf16* C = (z == 0) ? C0 : C1;
        float nwv[4];
        #pragma unroll
        for (int ni = 0; ni < 4; ++ni) nwv[ni] = hw[ni * 16 + r16];  // col % 64
        // fused per-head rmsnorm: each wave tile spans exactly one 64-wide head
        #pragma unroll
        for (int mi = 0; mi < 4; ++mi) {
            #pragma unroll
            for (int r = 0; r < 4; ++r) {
                float v[4], ss = 0.0f;
                #pragma unroll
                for (int ni = 0; ni < 4; ++ni) {
                    v[ni] = clipf(acc[mi][ni][r] + bv[ni]);
                    ss += v[ni] * v[ni];
                }
                ss += __shfl_xor(ss, 1, 64);
                ss += __shfl_xor(ss, 2, 64);
                ss += __shfl_xor(ss, 4, 64);
                ss += __shfl_xor(ss, 8, 64);
                float rms = sqrtf(fmaxf(ss * (1.0f / 64.0f), EPS) + EPS);
                int row = m0 + mwo + mi * 16 + quad * 4 + r;
                #pragma unroll
                for (int ni = 0; ni < 4; ++ni) {
                    int col = n0 + nwo + ni * 16 + r16;
                    C[(size_t)row * N + col] = (bf16)fin0(v[ni] / rms * nwv[ni]);
                }
            }
        }
    } else {
        // V: store transposed per head: VT[((b*16+h)*64 + hd)*1024 + token]
        const int b_ = m0 >> 10;            // block's rows lie in one batch
        const int tokbase = (m0 & 1023) + mwo;
        #pragma unroll
        for (int ni = 0; ni < 4; ++ni) {
            int col = n0 + nwo + ni * 16 + r16;
            int h_ = col >> 6, hd = col & 63;
            bf16* dst = VT + (((size_t)b_ * 16 + h_) * 64 + hd) * 1024;
            #pragma unroll
            for (int mi = 0; mi < 4; ++mi) {
                bf16x4 pack;
                #pragma unroll
                for (int r = 0; r < 4; ++r) pack[r] = (bf16)(acc[mi][ni][r] + bv[ni]);
                *(bf16x4*)&dst[tokbase + mi * 16 + quad * 4] = pack;
            }
        }
    }
}

// ---------------- fused FFN1 (double-buffered): g = silu(A@W1^T + b1) * (A@W3^T + b3) ----------------
// grid (M/128, 26), block 512. per-wave 64x32 per stream.
__global__ __launch_bounds__(512) void gemm_ffn1(const bf16* __restrict__ A,
                                                 const bf16* __restrict__ B1,
                                                 const bf16* __restrict__ B3,
                                                 const float* __restrict__ b1,
                                                 const float* __restrict__ b3,
                                                 bf16* __restrict__ G) {
    __shared__ __align__(16) bf16 sA[2][128 * 32];
    __shared__ __align__(16) bf16 sB1[2][128 * 32];
    __shared__ __align__(16) bf16 sB3[2][128 * 32];
    const int tid = threadIdx.x;
    const int w = tid >> 6, lane = tid & 63;
    const int m0 = blockIdx.x * 128;
    const int n0 = blockIdx.y * 128;
    const int mwo = (w >> 2) * 64, nwo = (w & 3) * 32;
    const int r16 = lane & 15, quad = lane >> 4;
    const int kreg = quad * 8;
    const int K = 1024, N = 3328;

    f32x4 zero = {0.f, 0.f, 0.f, 0.f};
    f32x4 acc1[4][2], acc3[4][2];
    #pragma unroll
    for (int i = 0; i < 4; ++i)
        #pragma unroll
        for (int j = 0; j < 2; ++j) { acc1[i][j] = zero; acc3[i][j] = zero; }

    const int arow = tid >> 2, akoff = (tid & 3) << 3;

    {
        async_copy16(&sA[0][tid * 8],  &A[(size_t)(m0 + arow) * K + akoff]);
        async_copy16(&sB1[0][tid * 8], &B1[(size_t)(n0 + arow) * K + akoff]);
        async_copy16(&sB3[0][tid * 8], &B3[(size_t)(n0 + arow) * K + akoff]);
    }
    for (int kt = 0; kt < 32; ++kt) {
        __syncthreads();
        const int cur = kt & 1, nxt = cur ^ 1;
        if (kt + 1 < 32) {
            const int kb = (kt + 1) << 5;
            async_copy16(&sA[nxt][tid * 8],  &A[(size_t)(m0 + arow) * K + kb + akoff]);
            async_copy16(&sB1[nxt][tid * 8], &B1[(size_t)(n0 + arow) * K + kb + akoff]);
            async_copy16(&sB3[nxt][tid * 8], &B3[(size_t)(n0 + arow) * K + kb + akoff]);
        }
        bf16x8 af[4], bf1[2], bf3[2];
        #pragma unroll
        for (int i = 0; i < 4; ++i)
            af[i]  = *(const bf16x8*)&sA[cur][(mwo + i * 16 + r16) * 32 + kreg];
        #pragma unroll
        for (int i = 0; i < 2; ++i) {
            bf1[i] = *(const bf16x8*)&sB1[cur][(nwo + i * 16 + r16) * 32 + kreg];
            bf3[i] = *(const bf16x8*)&sB3[cur][(nwo + i * 16 + r16) * 32 + kreg];
        }
        #pragma unroll
        for (int mi = 0; mi < 4; ++mi)
            #pragma unroll
            for (int ni = 0; ni < 2; ++ni) {
                acc1[mi][ni] = __builtin_amdgcn_mfma_f32_16x16x32_bf16(af[mi], bf1[ni], acc1[mi][ni], 0, 0, 0);
                acc3[mi][ni] = __builtin_amdgcn_mfma_f32_16x16x32_bf16(af[mi], bf3[ni], acc3[mi][ni], 0, 0, 0);
            }
    }

    #pragma unroll
    for (int ni = 0; ni < 2; ++ni) {
        int col = n0 + nwo + ni * 16 + r16;
        float bv1 = (col < 3280) ? b1[col] : 0.0f;
        float bv3 = (col < 3280) ? b3[col] : 0.0f;
        #pragma unroll
        for (int mi = 0; mi < 4; ++mi) {
            #pragma unroll
            for (int r = 0; r < 4; ++r) {
                int row = m0 + mwo + mi * 16 + quad * 4 + r;
                float z1 = acc1[mi][ni][r] + bv1;
                float z3 = acc3[mi][ni][r] + bv3;
                float s = z1 / (1.0f + __expf(-z1));
                G[(size_t)row * N + col] = (bf16)(s * z3);
            }
        }
    }
}

// ---------------- split-K GEMM (double-buffered) -> f32 partials ----------------
// grid (M/128, N/128, 2), block 256.
__global__ __launch_bounds__(256) void gemm_splitk(const bf16* __restrict__ A,
                                                   const bf16* __restrict__ B,
                                                   float* __restrict__ P,
                                                   int N, int K, int Kh) {
    const int s = blockIdx.z;
    __shared__ __align__(16) bf16 sA[2][128 * 32];
    __shared__ __align__(16) bf16 sB[2][128 * 32];
    const int tid = threadIdx.x;
    const int w = tid >> 6, lane = tid & 63;
    const int m0 = blockIdx.x * 128;
    const int n0 = blockIdx.y * 128;
    const int mwo = (w >> 1) * 64, nwo = (w & 1) * 64;
    const int r16 = lane & 15, quad = lane >> 4;
    const int kreg = quad * 8;
    const int kbase = s * Kh;

    f32x4 zero = {0.f, 0.f, 0.f, 0.f};
    f32x4 acc[4][4];
    #pragma unroll
    for (int i = 0; i < 4; ++i)
        #pragma unroll
        for (int j = 0; j < 4; ++j) acc[i][j] = zero;

    const int c0 = tid, c1 = tid + 256;
    const int am0 = c0 >> 2, ak0 = (c0 & 3) << 3;
    const int am1 = c1 >> 2, ak1 = (c1 & 3) << 3;
    const int kIters = Kh >> 5;

    {
        async_copy16(&sA[0][c0 * 8], &A[(size_t)(m0 + am0) * K + kbase + ak0]);
        async_copy16(&sA[0][c1 * 8], &A[(size_t)(m0 + am1) * K + kbase + ak1]);
        async_copy16(&sB[0][c0 * 8], &B[(size_t)(n0 + am0) * K + kbase + ak0]);
        async_copy16(&sB[0][c1 * 8], &B[(size_t)(n0 + am1) * K + kbase + ak1]);
    }
    for (int kt = 0; kt < kIters; ++kt) {
        __syncthreads();
        const int cur = kt & 1, nxt = cur ^ 1;
        if (kt + 1 < kIters) {
            const int kb = kbase + ((kt + 1) << 5);
            async_copy16(&sA[nxt][c0 * 8], &A[(size_t)(m0 + am0) * K + kb + ak0]);
            async_copy16(&sA[nxt][c1 * 8], &A[(size_t)(m0 + am1) * K + kb + ak1]);
            async_copy16(&sB[nxt][c0 * 8], &B[(size_t)(n0 + am0) * K + kb + ak0]);
            async_copy16(&sB[nxt][c1 * 8], &B[(size_t)(n0 + am1) * K + kb + ak1]);
        }
        bf16x8 af[4], bfr[4];
        #pragma unroll
        for (int i = 0; i < 4; ++i) {
            af[i]  = *(const bf16x8*)&sA[cur][(mwo + i * 16 + r16) * 32 + kreg];
            bfr[i] = *(const bf16x8*)&sB[cur][(nwo + i * 16 + r16) * 32 + kreg];
        }
        #pragma unroll
        for (int mi = 0; mi < 4; ++mi)
            #pragma unroll
            for (int ni = 0; ni < 4; ++ni)
                acc[mi][ni] = __builtin_amdgcn_mfma_f32_16x16x32_bf16(af[mi], bfr[ni], acc[mi][ni], 0, 0, 0);
    }

    float* Pz = P + (size_t)s * 4096 * 1024;
    #pragma unroll
    for (int mi = 0; mi < 4; ++mi)
        #pragma unroll
        for (int ni = 0; ni < 4; ++ni) {
            int col = n0 + nwo + ni * 16 + r16;
            #pragma unroll
            for (int r = 0; r < 4; ++r) {
                int row = m0 + mwo + mi * 16 + quad * 4 + r;
                Pz[(size_t)row * N + col] = acc[mi][ni][r];
            }
        }
}

// ---------------- windowed causal flash attention ----------------
// grid: (L/64, H, B), block 256. q/k: (B, L, H, 64); vt: (B, H, 64, L) bf16.
__global__ __launch_bounds__(256) void attn_win(const bf16* __restrict__ q,
                                                const bf16* __restrict__ k,
                                                const bf16* __restrict__ vt,
                                                const int* __restrict__ winp,
                                                bf16* __restrict__ o) {
    __shared__ __align__(16) bf16 sQ[64 * 64];
    __shared__ __align__(16) bf16 sK[64 * 64];
    __shared__ __align__(16) bf16 sVt[64 * 80];
    __shared__ __align__(16) bf16 sP[64 * 64];
    const int tid = threadIdx.x, w = tid >> 6, lane = tid & 63;
    const int qt = blockIdx.x, h = blockIdx.y, b = blockIdx.z;
    const int q0 = qt * 64;
    const int win = *winp;
    const float scale = 0.125f;  // 64^-0.5
    const int r16 = lane & 15, quad = lane >> 4;

    // stage Q (async; lds dst linear in tid)
    {
        int qr0 = tid >> 3, col0 = (tid & 7) * 8;
        async_copy16(&sQ[tid * 8], &q[(((size_t)b * 1024 + q0 + qr0) * 16 + h) * 64 + col0]);
        int c1 = tid + 256;
        int qr1 = c1 >> 3, col1 = (c1 & 7) * 8;
        async_copy16(&sQ[c1 * 8], &q[(((size_t)b * 1024 + q0 + qr1) * 16 + h) * 64 + col1]);
    }
    __syncthreads();
    bf16x8 aq0 = *(const bf16x8*)&sQ[(w * 16 + r16) * 64 + quad * 8];
    bf16x8 aq1 = *(const bf16x8*)&sQ[(w * 16 + r16) * 64 + 32 + quad * 8];

    float M[4], Lr[4];
    f32x4 zero = {0.f, 0.f, 0.f, 0.f};
    f32x4 accO[4];
    #pragma unroll
    for (int r = 0; r < 4; ++r) { M[r] = -INFINITY; Lr[r] = 0.0f; }
    #pragma unroll
    for (int nf = 0; nf < 4; ++nf) accO[nf] = zero;

    int lo = q0 - (win - 1); if (lo < 0) lo = 0;
    const int kt0 = lo >> 6;
    const bf16* vth = vt + ((size_t)b * 16 + h) * 64 * 1024;

    for (int kt = kt0; kt <= qt; ++kt) {
        __syncthreads();
        {
            int kr0 = tid >> 3, col0 = (tid & 7) * 8;
            async_copy16(&sK[tid * 8], &k[(((size_t)b * 1024 + kt * 64 + kr0) * 16 + h) * 64 + col0]);
            int c1 = tid + 256;
            int kr1 = c1 >> 3, col1 = (c1 & 7) * 8;
            async_copy16(&sK[c1 * 8], &k[(((size_t)b * 1024 + kt * 64 + kr1) * 16 + h) * 64 + col1]);
        }
        // Vt: rows = hd (64), cols = key (64), row stride 80 elems (b128-aligned, 4-way banks)
        #pragma unroll
        for (int c = tid; c < 512; c += 256) {
            int hd = c >> 3, koff = (c & 7) * 8;
            *(u32x4*)&sVt[hd * 80 + koff] = *(const u32x4*)&vth[(size_t)hd * 1024 + kt * 64 + koff];
        }
        __syncthreads();

        f32x4 sf[4];
        #pragma unroll
        for (int nf = 0; nf < 4; ++nf) {
            bf16x8 bk0 = *(const bf16x8*)&sK[(nf * 16 + r16) * 64 + quad * 8];
            bf16x8 bk1 = *(const bf16x8*)&sK[(nf * 16 + r16) * 64 + 32 + quad * 8];
            f32x4 accS = zero;
            accS = __builtin_amdgcn_mfma_f32_16x16x32_bf16(aq0, bk0, accS, 0, 0, 0);
            accS = __builtin_amdgcn_mfma_f32_16x16x32_bf16(aq1, bk1, accS, 0, 0, 0);
            sf[nf] = accS;
        }

        #pragma unroll
        for (int r = 0; r < 4; ++r) {
            int i = q0 + w * 16 + quad * 4 + r;
            float p[4];
            float rowmax = -INFINITY;
            #pragma unroll
            for (int nf = 0; nf < 4; ++nf) {
                int j = kt * 64 + nf * 16 + r16;
                bool ok = (j <= i) && (i - j < win);
                float sv = ok ? sf[nf][r] * scale : -INFINITY;
                p[nf] = sv;
                rowmax = fmaxf(rowmax, sv);
            }
            #pragma unroll
            for (int off = 1; off < 16; off <<= 1)
                rowmax = fmaxf(rowmax, __shfl_xor(rowmax, off, 64));
            float mnew = fmaxf(M[r], rowmax);
            float alpha = (mnew == M[r]) ? 1.0f : __expf(M[r] - mnew);
            float rs = 0.0f;
            #pragma unroll
            for (int nf = 0; nf < 4; ++nf) {
                float pv = (p[nf] == -INFINITY) ? 0.0f : __expf(p[nf] - mnew);
                rs += pv;
                sP[(w * 16 + quad * 4 + r) * 64 + nf * 16 + r16] = (bf16)pv;
            }
            #pragma unroll
            for (int off = 1; off < 16; off <<= 1) rs += __shfl_xor(rs, off, 64);
            Lr[r] = Lr[r] * alpha + rs;
            M[r] = mnew;
            #pragma unroll
            for (int nf = 0; nf < 4; ++nf) accO[nf][r] = accO[nf][r] * alpha;
        }
        __syncthreads();

        bf16x8 ap0 = *(const bf16x8*)&sP[(w * 16 + r16) * 64 + quad * 8];
        bf16x8 ap1 = *(const bf16x8*)&sP[(w * 16 + r16) * 64 + 32 + quad * 8];
        #pragma unroll
        for (int nf = 0; nf < 4; ++nf) {
            bf16x8 bv0 = *(const bf16x8*)&sVt[(nf * 16 + r16) * 80 + quad * 8];
            bf16x8 bv1 = *(const bf16x8*)&sVt[(nf * 16 + r16) * 80 + 32 + quad * 8];
            accO[nf] = __builtin_amdgcn_mfma_f32_16x16x32_bf16(ap0, bv0, accO[nf], 0, 0, 0);
            accO[nf] = __builtin_amdgcn_mfma_f32_16x16x32_bf16(ap1, bv1, accO[nf], 0, 0, 0);
        }
    }

    #pragma unroll
    for (int r = 0; r < 4; ++r) {
        float inv = (Lr[r] > 0.0f) ? 1.0f / Lr[r] : 0.0f;
        int row = q0 + w * 16 + quad * 4 + r;
        #pragma unroll
        for (int nf = 0; nf < 4; ++nf) {
            float ov = fin0(accO[nf][r] * inv);
            o[(((size_t)b * 1024 + row) * 16 + h) * 64 + nf * 16 + r16] = (bf16)ov;
        }
    }
}

extern "C" void kernel_launch(void* const* d_in, const int* in_sizes, int n_in,
                              void* d_out, int out_size, void* d_ws, size_t ws_size,
                              hipStream_t stream) {
    const float* x       = (const float*)d_in[0];
    const float* wq_w    = (const float*)d_in[1];
    const float* wq_b    = (const float*)d_in[2];
    const float* wk_w    = (const float*)d_in[3];
    const float* wk_b    = (const float*)d_in[4];
    const float* wv_w    = (const float*)d_in[5];
    const float* wv_b    = (const float*)d_in[6];
    const float* wo_w    = (const float*)d_in[7];
    const float* wo_b    = (const float*)d_in[8];
    const float* q_norm_w= (const float*)d_in[9];
    const float* k_norm_w= (const float*)d_in[10];
    const float* seq_norm_w      = (const float*)d_in[11];
    const float* seq_post_norm_w = (const float*)d_in[12];
    const float* ffn_norm_w      = (const float*)d_in[13];
    const float* ffn_post_norm_w = (const float*)d_in[14];
    const float* w1_w    = (const float*)d_in[15];
    const float* w1_b    = (const float*)d_in[16];
    const float* w2_w    = (const float*)d_in[17];
    const float* w2_b    = (const float*)d_in[18];
    const float* w3_w    = (const float*)d_in[19];
    const float* w3_b    = (const float*)d_in[20];
    const int*   winp    = (const int*)d_in[21];
    float* out = (float*)d_out;

    const size_t SZ_W   = 2097152;    // 1024*1024*2
    const size_t SZ_WP  = 6815744;    // 3328*1024*2
    const size_t SZ_ACT = 8388608;    // 4096*1024*2
    const size_t SZ_H   = 16777216;   // 4096*1024*4
    const size_t SZ_P   = 33554432;   // 2*4096*1024*4

    char* p = (char*)d_ws;
    bf16* Wq  = (bf16*)p; p += SZ_W;
    bf16* Wk  = (bf16*)p; p += SZ_W;
    bf16* Wv  = (bf16*)p; p += SZ_W;
    bf16* Wo  = (bf16*)p; p += SZ_W;
    bf16* W1p = (bf16*)p; p += SZ_WP;
    bf16* W3p = (bf16*)p; p += SZ_WP;
    bf16* W2p = (bf16*)p; p += SZ_WP;
    float* h  = (float*)p; p += SZ_H;
    bf16* hn  = (bf16*)p; p += SZ_ACT;
    float* part = (float*)p; p += SZ_P;   // split-K partials (O-proj, then FFN2)
    char* regionA = p;  // aliased: attn-phase buffers, later g
    bf16* xn    = (bf16*)(regionA);
    bf16* qb    = (bf16*)(regionA + 1 * SZ_ACT);
    bf16* kb    = (bf16*)(regionA + 2 * SZ_ACT);
    bf16* vtb   = (bf16*)(regionA + 3 * SZ_ACT);   // transposed V: (B,H,64,L)
    bf16* attnb = (bf16*)(regionA + 4 * SZ_ACT);
    bf16* g     = (bf16*)(regionA);   // 4096*3328*2 = 27.3 MB, reuses xn..attnb

    dim3 blk(256);

    // weight conversion
    convert4<<<dim3(1024, 1, 4), blk, 0, stream>>>(wq_w, wk_w, wv_w, wo_w, Wq, Wk, Wv, Wo);
    convert_w13<<<dim3(3328, 1, 2), blk, 0, stream>>>(w1_w, w3_w, W1p, W3p);
    convert_w2<<<dim3(1024, 4, 1), blk, 0, stream>>>(w2_w, W2p);

    // xn = rmsnorm(x, seq_norm_w)
    rmsnorm_in<<<4096, blk, 0, stream>>>(x, seq_norm_w, xn);

    // q/k/v projections; q,k head-normed; v written transposed
    gemm_qkv<<<dim3(32, 8, 3), blk, 0, stream>>>(xn, Wq, Wk, Wv, wq_b, wk_b, wv_b,
                                                 q_norm_w, k_norm_w, qb, kb, vtb);

    // windowed causal attention
    attn_win<<<dim3(16, 16, 4), blk, 0, stream>>>(qb, kb, vtb, winp, attnb);

    // output projection, split-K=2 -> f32 partials
    gemm_splitk<<<dim3(32, 8, 2), blk, 0, stream>>>(attnb, Wo, part, 1024, 1024, 512);

    // h = x + rmsnorm(p0+p1+wo_b, seq_post); hn = rmsnorm(h, ffn_norm)
    resid_norm<true><<<4096, blk, 0, stream>>>(x, part, part + 4096 * 1024, wo_b,
                                               seq_post_norm_w, ffn_norm_w, h, hn);

    // fused FFN1: g = silu(hn@W1^T+b1) * (hn@W3^T+b3), 512-thread blocks, dbuf
    gemm_ffn1<<<dim3(32, 26), dim3(512), 0, stream>>>(hn, W1p, W3p, w1_b, w3_b, g);

    // FFN2: split-K=2 over K=3328 -> f32 partials
    gemm_splitk<<<dim3(32, 8, 2), blk, 0, stream>>>(g, W2p, part, 1024, 3328, 1664);

    // out = h + rmsnorm(p0+p1+w2_b, ffn_post)
    resid_norm<false><<<4096, blk, 0, stream>>>(h, part, part + 4096 * 1024, w2_b,
                                                ffn_post_norm_w, nullptr, out, nullptr);
}